// Round 1
// baseline (5513.922 us; speedup 1.0000x reference)
//
#include <hip/hip_runtime.h>
#include <hip/hip_bf16.h>

#define D 64

// ---------------------------------------------------------------------------
// Edge kernel: thread-per-edge full MLP + fused scatter.
//   hidden = relu([h_src;h_dst] @ We1 + be1)   (K=128)
//   msg    = hidden @ We2 + be2                 (K=64)
//   atomicAdd(h_neigh[dst], h_src * msg)
// Weights indexed wave-uniformly -> compiler emits s_load; VALU is pure fmac.
// ---------------------------------------------------------------------------
__global__ __launch_bounds__(256) void edge_kernel(
    const float* __restrict__ x,
    const float* __restrict__ We1, const float* __restrict__ be1,
    const float* __restrict__ We2, const float* __restrict__ be2,
    const int* __restrict__ src, const int* __restrict__ dst,
    float* __restrict__ hneigh, int E)
{
    int e = blockIdx.x * 256 + threadIdx.x;
    if (e >= E) return;
    int s = src[e];
    int d = dst[e];
    const float* xs = x + (size_t)s * D;
    const float* xd = x + (size_t)d * D;

    float hid[D];
#pragma unroll
    for (int j = 0; j < D; ++j) hid[j] = be1[j];

    // GEMM1 phase 1: h_src rows 0..63 of We1
    for (int k = 0; k < D; k += 4) {
        float4 a = *(const float4*)(xs + k);
#pragma unroll
        for (int j = 0; j < D; ++j) hid[j] += a.x * We1[(k + 0) * D + j];
#pragma unroll
        for (int j = 0; j < D; ++j) hid[j] += a.y * We1[(k + 1) * D + j];
#pragma unroll
        for (int j = 0; j < D; ++j) hid[j] += a.z * We1[(k + 2) * D + j];
#pragma unroll
        for (int j = 0; j < D; ++j) hid[j] += a.w * We1[(k + 3) * D + j];
    }
    // GEMM1 phase 2: h_dst rows 64..127 of We1
    for (int k = 0; k < D; k += 4) {
        float4 a = *(const float4*)(xd + k);
#pragma unroll
        for (int j = 0; j < D; ++j) hid[j] += a.x * We1[(D + k + 0) * D + j];
#pragma unroll
        for (int j = 0; j < D; ++j) hid[j] += a.y * We1[(D + k + 1) * D + j];
#pragma unroll
        for (int j = 0; j < D; ++j) hid[j] += a.z * We1[(D + k + 2) * D + j];
#pragma unroll
        for (int j = 0; j < D; ++j) hid[j] += a.w * We1[(D + k + 3) * D + j];
    }
#pragma unroll
    for (int j = 0; j < D; ++j) hid[j] = fmaxf(hid[j], 0.0f);

    // GEMM2 fused with u_mul_e + scatter, 4 outputs at a time.
    float* hd = hneigh + (size_t)d * D;
#pragma unroll 1
    for (int j0 = 0; j0 < D; j0 += 4) {
        float m0 = be2[j0 + 0];
        float m1 = be2[j0 + 1];
        float m2 = be2[j0 + 2];
        float m3 = be2[j0 + 3];
#pragma unroll
        for (int k = 0; k < D; ++k) {
            float h = hid[k];
            m0 += h * We2[k * D + j0 + 0];
            m1 += h * We2[k * D + j0 + 1];
            m2 += h * We2[k * D + j0 + 2];
            m3 += h * We2[k * D + j0 + 3];
        }
        float4 xv = *(const float4*)(xs + j0);
        atomicAdd(hd + j0 + 0, xv.x * m0);
        atomicAdd(hd + j0 + 1, xv.y * m1);
        atomicAdd(hd + j0 + 2, xv.z * m2);
        atomicAdd(hd + j0 + 3, xv.w * m3);
    }
}

// ---------------------------------------------------------------------------
// Node kernel: h2 = relu(h_neigh @ Wn + bn) in-place; gate = h2 @ Wg + bg
// ---------------------------------------------------------------------------
__global__ __launch_bounds__(256) void node_kernel(
    float* __restrict__ hneigh,  // [N,D] in: h_neigh, out: h2
    const float* __restrict__ Wn, const float* __restrict__ bn,
    const float* __restrict__ Wg, const float* __restrict__ bg,
    float* __restrict__ gate, int N)
{
    int n = blockIdx.x * 256 + threadIdx.x;
    if (n >= N) return;
    float* row = hneigh + (size_t)n * D;

    float hn[D];
#pragma unroll
    for (int k = 0; k < D; k += 4) {
        float4 v = *(const float4*)(row + k);
        hn[k + 0] = v.x; hn[k + 1] = v.y; hn[k + 2] = v.z; hn[k + 3] = v.w;
    }

    float g = bg[0];
#pragma unroll 1
    for (int j0 = 0; j0 < D; j0 += 4) {
        float a0 = bn[j0 + 0];
        float a1 = bn[j0 + 1];
        float a2 = bn[j0 + 2];
        float a3 = bn[j0 + 3];
#pragma unroll
        for (int k = 0; k < D; ++k) {
            float h = hn[k];
            a0 += h * Wn[k * D + j0 + 0];
            a1 += h * Wn[k * D + j0 + 1];
            a2 += h * Wn[k * D + j0 + 2];
            a3 += h * Wn[k * D + j0 + 3];
        }
        a0 = fmaxf(a0, 0.0f);
        a1 = fmaxf(a1, 0.0f);
        a2 = fmaxf(a2, 0.0f);
        a3 = fmaxf(a3, 0.0f);
        g += a0 * Wg[j0 + 0] + a1 * Wg[j0 + 1] + a2 * Wg[j0 + 2] + a3 * Wg[j0 + 3];
        float4 o; o.x = a0; o.y = a1; o.z = a2; o.w = a3;
        *(float4*)(row + j0) = o;
    }
    gate[n] = g;
}

// ---------------------------------------------------------------------------
// Pool kernel: one block per graph. Binary-search segment bounds in sorted
// graph_ids, per-graph softmax over gates, weighted sum of h2, then fused
// classifier out = pooled @ Wfc + bfc.
// ---------------------------------------------------------------------------
__global__ __launch_bounds__(256) void pool_kernel(
    const float* __restrict__ h2,    // [N,D]
    const float* __restrict__ gate,  // [N]
    const int* __restrict__ gid,     // [N] sorted
    const float* __restrict__ Wfc, const float* __restrict__ bfc,
    float* __restrict__ out, int N, int C)
{
    int g = blockIdx.x;
    int tid = threadIdx.x;

    // lower_bound(gid, g) and lower_bound(gid, g+1); redundant per thread.
    int lo = 0, hi = N;
    while (lo < hi) { int mid = (lo + hi) >> 1; if (gid[mid] < g) lo = mid + 1; else hi = mid; }
    int s = lo;
    hi = N;
    while (lo < hi) { int mid = (lo + hi) >> 1; if (gid[mid] < g + 1) lo = mid + 1; else hi = mid; }
    int e = lo;

    __shared__ float red[256];
    __shared__ float accs[4][D];
    __shared__ float dens[4];

    // phase 1: segment max of gate
    float m = -INFINITY;
    for (int i = s + tid; i < e; i += 256) m = fmaxf(m, gate[i]);
    red[tid] = m;
    __syncthreads();
    for (int w = 128; w > 0; w >>= 1) {
        if (tid < w) red[tid] = fmaxf(red[tid], red[tid + w]);
        __syncthreads();
    }
    float gmax = red[0];
    __syncthreads();

    // phase 2: denom + weighted feature sum (4 node-groups x 64 features)
    int f = tid & (D - 1);
    int grp = tid >> 6;
    float acc = 0.0f, den = 0.0f;
    for (int i = s + grp; i < e; i += 4) {
        float w = expf(gate[i] - gmax);
        acc += w * h2[(size_t)i * D + f];
        if (f == 0) den += w;
    }
    accs[grp][f] = acc;
    if (f == 0) dens[grp] = den;
    __syncthreads();

    if (tid < D) {
        float p = accs[0][tid] + accs[1][tid] + accs[2][tid] + accs[3][tid];
        float dn = dens[0] + dens[1] + dens[2] + dens[3];
        p = (e > s) ? (p / dn) : 0.0f;  // empty graph -> pooled = 0 -> out = bfc
        red[tid] = p;
    }
    __syncthreads();

    if (tid < C) {
        float o = bfc[tid];
#pragma unroll
        for (int k = 0; k < D; ++k) o += red[k] * Wfc[k * C + tid];
        out[g * C + tid] = o;
    }
}

extern "C" void kernel_launch(void* const* d_in, const int* in_sizes, int n_in,
                              void* d_out, int out_size, void* d_ws, size_t ws_size,
                              hipStream_t stream) {
    const float* x   = (const float*)d_in[0];
    const float* We1 = (const float*)d_in[1];
    const float* be1 = (const float*)d_in[2];
    const float* We2 = (const float*)d_in[3];
    const float* be2 = (const float*)d_in[4];
    const float* Wn  = (const float*)d_in[5];
    const float* bn  = (const float*)d_in[6];
    const float* Wg  = (const float*)d_in[7];
    const float* bg  = (const float*)d_in[8];
    const float* Wfc = (const float*)d_in[9];
    const float* bfc = (const float*)d_in[10];
    const int* src = (const int*)d_in[11];
    const int* dst = (const int*)d_in[12];
    const int* gid = (const int*)d_in[13];

    const int N = in_sizes[0] / D;
    const int E = in_sizes[11];
    const int C = 10;
    const int G = out_size / C;

    float* hneigh = (float*)d_ws;                 // [N,D], becomes h2 in-place
    float* gate   = hneigh + (size_t)N * D;       // [N]
    float* outp   = (float*)d_out;

    hipMemsetAsync(hneigh, 0, (size_t)N * D * sizeof(float), stream);

    edge_kernel<<<(E + 255) / 256, 256, 0, stream>>>(x, We1, be1, We2, be2,
                                                     src, dst, hneigh, E);
    node_kernel<<<(N + 255) / 256, 256, 0, stream>>>(hneigh, Wn, bn, Wg, bg,
                                                     gate, N);
    pool_kernel<<<G, 256, 0, stream>>>(hneigh, gate, gid, Wfc, bfc, outp, N, C);
}

// Round 2
// 3690.898 us; speedup vs baseline: 1.4939x; 1.4939x over previous
//
#include <hip/hip_runtime.h>
#include <hip/hip_bf16.h>

#define D 64

// ---------------------------------------------------------------------------
// Prep: transpose We2 and Wn into workspace so j-runtime GEMM loops read
// contiguous 64-float rows (wave-uniform s_load-able).
// ---------------------------------------------------------------------------
__global__ void prep_transpose(const float* __restrict__ We2,
                               const float* __restrict__ Wn,
                               float* __restrict__ We2T,
                               float* __restrict__ WnT)
{
    int t = blockIdx.x * 256 + threadIdx.x;
    if (t < D * D) {
        int k = t / D, j = t % D;
        We2T[j * D + k] = We2[k * D + j];
        WnT [j * D + k] = Wn [k * D + j];
    }
}

// ---------------------------------------------------------------------------
// CSR build: histogram of dst, exclusive scan, fill edge-index list.
// ---------------------------------------------------------------------------
__global__ void hist_kernel(const int* __restrict__ dst, int* __restrict__ deg, int E)
{
    int e = blockIdx.x * 256 + threadIdx.x;
    if (e < E) atomicAdd(&deg[dst[e]], 1);
}

__global__ __launch_bounds__(1024) void scan_kernel(
    const int* __restrict__ deg, int* __restrict__ off,
    int* __restrict__ cursor, int N)
{
    __shared__ int lds[1024];
    int tid = threadIdx.x;
    int chunk = (N + 1023) >> 10;
    int b = tid * chunk;
    int e = min(b + chunk, N);
    int s = 0;
    for (int i = b; i < e; ++i) s += deg[i];
    lds[tid] = s;
    __syncthreads();
    for (int d2 = 1; d2 < 1024; d2 <<= 1) {
        int v = 0;
        if (tid >= d2) v = lds[tid - d2];
        __syncthreads();
        lds[tid] += v;
        __syncthreads();
    }
    int run = (tid == 0) ? 0 : lds[tid - 1];
    for (int i = b; i < e; ++i) {
        off[i] = run;
        cursor[i] = run;
        run += deg[i];
    }
    if (tid == 1023) off[N] = lds[1023];
}

__global__ void fill_kernel(const int* __restrict__ dst, int* __restrict__ cursor,
                            int* __restrict__ eidx, int E)
{
    int e = blockIdx.x * 256 + threadIdx.x;
    if (e < E) {
        int p = atomicAdd(&cursor[dst[e]], 1);
        eidx[p] = e;
    }
}

// ---------------------------------------------------------------------------
// Gather-side edge MLP: one thread per destination node. Recompute each
// in-edge's message and accumulate into this node's own h_neigh row.
// No fp32 atomics anywhere. Weight indices are wave-uniform -> s_load.
// ---------------------------------------------------------------------------
__global__ __launch_bounds__(256) void gather_edge_kernel(
    const float* __restrict__ x,
    const float* __restrict__ We1, const float* __restrict__ be1,
    const float* __restrict__ We2T, const float* __restrict__ be2,
    const int* __restrict__ off, const int* __restrict__ eidx,
    const int* __restrict__ src,
    float* __restrict__ hneigh, int N)
{
    int n = blockIdx.x * 256 + threadIdx.x;
    if (n >= N) return;
    float* row = hneigh + (size_t)n * D;
#pragma unroll
    for (int j = 0; j < D; j += 4) *(float4*)(row + j) = make_float4(0.f, 0.f, 0.f, 0.f);

    int beg = off[n], end = off[n + 1];
    const float* xd = x + (size_t)n * D;

    for (int i = beg; i < end; ++i) {
        int e = eidx[i];
        const float* xs = x + (size_t)src[e] * D;

        float hid[D];
#pragma unroll
        for (int j = 0; j < D; ++j) hid[j] = be1[j];

        // GEMM1, src half: k runtime (uniform) so We1 row comes via s_load.
#pragma unroll 1
        for (int k = 0; k < D; ++k) {
            float a = xs[k];
            const float* w = We1 + k * D;
#pragma unroll
            for (int j = 0; j < D; ++j) hid[j] += a * w[j];
        }
        // GEMM1, dst half.
#pragma unroll 1
        for (int k = 0; k < D; ++k) {
            float a = xd[k];
            const float* w = We1 + (D + k) * D;
#pragma unroll
            for (int j = 0; j < D; ++j) hid[j] += a * w[j];
        }
#pragma unroll
        for (int j = 0; j < D; ++j) hid[j] = fmaxf(hid[j], 0.f);

        // GEMM2 + u_mul_e + accumulate into own row (L1-resident RMW).
#pragma unroll 1
        for (int j = 0; j < D; ++j) {
            const float* w = We2T + j * D;
            float m = be2[j];
#pragma unroll
            for (int k = 0; k < D; ++k) m += hid[k] * w[k];
            row[j] += xs[j] * m;
        }
    }
}

// ---------------------------------------------------------------------------
// Node MLP: h2 = relu(h_neigh @ Wn + bn) in place; gate = h2 @ Wg + bg.
// ---------------------------------------------------------------------------
__global__ __launch_bounds__(256) void node_kernel(
    float* __restrict__ hneigh,
    const float* __restrict__ WnT, const float* __restrict__ bn,
    const float* __restrict__ Wg, const float* __restrict__ bg,
    float* __restrict__ gate, int N)
{
    int n = blockIdx.x * 256 + threadIdx.x;
    if (n >= N) return;
    float* row = hneigh + (size_t)n * D;

    float hn[D];
#pragma unroll
    for (int k = 0; k < D; k += 4) {
        float4 v = *(const float4*)(row + k);
        hn[k] = v.x; hn[k + 1] = v.y; hn[k + 2] = v.z; hn[k + 3] = v.w;
    }
    float g = bg[0];
#pragma unroll 1
    for (int j = 0; j < D; ++j) {
        const float* w = WnT + j * D;
        float a = bn[j];
#pragma unroll
        for (int k = 0; k < D; ++k) a += hn[k] * w[k];
        a = fmaxf(a, 0.f);
        g += a * Wg[j];
        row[j] = a;
    }
    gate[n] = g;
}

// ---------------------------------------------------------------------------
// Pool: one block per graph; binary-search segment, softmax over gates,
// weighted sum, fused classifier.
// ---------------------------------------------------------------------------
__global__ __launch_bounds__(256) void pool_kernel(
    const float* __restrict__ h2,
    const float* __restrict__ gate,
    const int* __restrict__ gid,
    const float* __restrict__ Wfc, const float* __restrict__ bfc,
    float* __restrict__ out, int N, int C)
{
    int g = blockIdx.x;
    int tid = threadIdx.x;

    int lo = 0, hi = N;
    while (lo < hi) { int mid = (lo + hi) >> 1; if (gid[mid] < g) lo = mid + 1; else hi = mid; }
    int s = lo;
    hi = N;
    while (lo < hi) { int mid = (lo + hi) >> 1; if (gid[mid] < g + 1) lo = mid + 1; else hi = mid; }
    int e = lo;

    __shared__ float red[256];
    __shared__ float accs[4][D];
    __shared__ float dens[4];

    float m = -INFINITY;
    for (int i = s + tid; i < e; i += 256) m = fmaxf(m, gate[i]);
    red[tid] = m;
    __syncthreads();
    for (int w = 128; w > 0; w >>= 1) {
        if (tid < w) red[tid] = fmaxf(red[tid], red[tid + w]);
        __syncthreads();
    }
    float gmax = red[0];
    __syncthreads();

    int f = tid & (D - 1);
    int grp = tid >> 6;
    float acc = 0.0f, den = 0.0f;
    for (int i = s + grp; i < e; i += 4) {
        float w = expf(gate[i] - gmax);
        acc += w * h2[(size_t)i * D + f];
        if (f == 0) den += w;
    }
    accs[grp][f] = acc;
    if (f == 0) dens[grp] = den;
    __syncthreads();

    if (tid < D) {
        float p = accs[0][tid] + accs[1][tid] + accs[2][tid] + accs[3][tid];
        float dn = dens[0] + dens[1] + dens[2] + dens[3];
        p = (e > s) ? (p / dn) : 0.0f;
        red[tid] = p;
    }
    __syncthreads();

    if (tid < C) {
        float o = bfc[tid];
#pragma unroll
        for (int k = 0; k < D; ++k) o += red[k] * Wfc[k * C + tid];
        out[g * C + tid] = o;
    }
}

extern "C" void kernel_launch(void* const* d_in, const int* in_sizes, int n_in,
                              void* d_out, int out_size, void* d_ws, size_t ws_size,
                              hipStream_t stream) {
    const float* x   = (const float*)d_in[0];
    const float* We1 = (const float*)d_in[1];
    const float* be1 = (const float*)d_in[2];
    const float* We2 = (const float*)d_in[3];
    const float* be2 = (const float*)d_in[4];
    const float* Wn  = (const float*)d_in[5];
    const float* bn  = (const float*)d_in[6];
    const float* Wg  = (const float*)d_in[7];
    const float* bg  = (const float*)d_in[8];
    const float* Wfc = (const float*)d_in[9];
    const float* bfc = (const float*)d_in[10];
    const int* src = (const int*)d_in[11];
    const int* dst = (const int*)d_in[12];
    const int* gid = (const int*)d_in[13];

    const int N = in_sizes[0] / D;
    const int E = in_sizes[11];
    const int C = 10;
    const int G = out_size / C;

    float* hneigh = (float*)d_ws;                      // [N*D]
    float* gate   = hneigh + (size_t)N * D;            // [N]
    float* We2T   = gate + N;                          // [D*D]
    float* WnT    = We2T + D * D;                      // [D*D]
    int*   deg    = (int*)(WnT + D * D);               // [N]
    int*   off    = deg + N;                           // [N+1]
    int*   cursor = off + N + 1;                       // [N]
    int*   eidx   = cursor + N;                        // [E]
    float* outp   = (float*)d_out;

    hipMemsetAsync(deg, 0, (size_t)N * sizeof(int), stream);

    prep_transpose<<<(D * D + 255) / 256, 256, 0, stream>>>(We2, Wn, We2T, WnT);
    hist_kernel<<<(E + 255) / 256, 256, 0, stream>>>(dst, deg, E);
    scan_kernel<<<1, 1024, 0, stream>>>(deg, off, cursor, N);
    fill_kernel<<<(E + 255) / 256, 256, 0, stream>>>(dst, cursor, eidx, E);
    gather_edge_kernel<<<(N + 255) / 256, 256, 0, stream>>>(
        x, We1, be1, We2T, be2, off, eidx, src, hneigh, N);
    node_kernel<<<(N + 255) / 256, 256, 0, stream>>>(hneigh, WnT, bn, Wg, bg, gate, N);
    pool_kernel<<<G, 256, 0, stream>>>(hneigh, gate, gid, Wfc, bfc, outp, N, C);
}

// Round 3
// 3016.764 us; speedup vs baseline: 1.8278x; 1.2235x over previous
//
#include <hip/hip_runtime.h>
#include <hip/hip_bf16.h>

#define D 64
#define LSTRIDE 65   // 65 % 32 == 1 -> bank = (lane + k) % 32 -> 2-way (free)

// ---------------------------------------------------------------------------
// CSR build: histogram of dst, exclusive scan, fill src-list grouped by dst.
// ---------------------------------------------------------------------------
__global__ void hist_kernel(const int* __restrict__ dst, int* __restrict__ deg, int E)
{
    int e = blockIdx.x * 256 + threadIdx.x;
    if (e < E) atomicAdd(&deg[dst[e]], 1);
}

__global__ __launch_bounds__(1024) void scan_kernel(
    const int* __restrict__ deg, int* __restrict__ off,
    int* __restrict__ cursor, int N)
{
    __shared__ int lds[1024];
    int tid = threadIdx.x;
    int chunk = (N + 1023) >> 10;
    int b = tid * chunk;
    int e = min(b + chunk, N);
    int s = 0;
    for (int i = b; i < e; ++i) s += deg[i];
    lds[tid] = s;
    __syncthreads();
    for (int d2 = 1; d2 < 1024; d2 <<= 1) {
        int v = 0;
        if (tid >= d2) v = lds[tid - d2];
        __syncthreads();
        lds[tid] += v;
        __syncthreads();
    }
    int run = (tid == 0) ? 0 : lds[tid - 1];
    for (int i = b; i < e; ++i) {
        off[i] = run;
        cursor[i] = run;
        run += deg[i];
    }
    if (tid == 1023) off[N] = lds[1023];
}

__global__ void fill_kernel(const int* __restrict__ dst, const int* __restrict__ src,
                            int* __restrict__ cursor, int* __restrict__ esrc, int E)
{
    int e = blockIdx.x * 256 + threadIdx.x;
    if (e < E) {
        int p = atomicAdd(&cursor[dst[e]], 1);
        esrc[p] = src[e];
    }
}

// ---------------------------------------------------------------------------
// Degree counting-sort (descending) -> perm[], so each wave's 64 lanes have
// near-equal in-degree (lane efficiency ~57% -> ~95%).
// ---------------------------------------------------------------------------
__global__ void dhist_kernel(const int* __restrict__ deg, int* __restrict__ dhist, int N)
{
    int n = blockIdx.x * 256 + threadIdx.x;
    if (n < N) atomicAdd(&dhist[255 - min(deg[n], 255)], 1);
}

__global__ void dscan_kernel(const int* __restrict__ dhist, int* __restrict__ dcur)
{
    __shared__ int lds[256];
    int tid = threadIdx.x;
    lds[tid] = dhist[tid];
    __syncthreads();
    for (int d2 = 1; d2 < 256; d2 <<= 1) {
        int v = (tid >= d2) ? lds[tid - d2] : 0;
        __syncthreads();
        lds[tid] += v;
        __syncthreads();
    }
    dcur[tid] = (tid == 0) ? 0 : lds[tid - 1];
}

__global__ void dscatter_kernel(const int* __restrict__ deg, int* __restrict__ dcur,
                                int* __restrict__ perm, int N)
{
    int n = blockIdx.x * 256 + threadIdx.x;
    if (n < N) {
        int b = 255 - min(deg[n], 255);
        int p = atomicAdd(&dcur[b], 1);
        perm[p] = n;
    }
}

// ---------------------------------------------------------------------------
// Gather-side edge MLP, register accumulator, per-thread LDS hidden row.
// One thread per destination node (degree-sorted via perm).
// ---------------------------------------------------------------------------
__global__ __launch_bounds__(128) void gather_edge_kernel(
    const float* __restrict__ x,
    const float* __restrict__ We1, const float* __restrict__ be1,
    const float* __restrict__ We2, const float* __restrict__ be2,
    const int* __restrict__ off, const int* __restrict__ esrc,
    const int* __restrict__ perm,
    float* __restrict__ hneigh, int N)
{
    __shared__ float hbuf[128 * LSTRIDE];
    float* hl = hbuf + threadIdx.x * LSTRIDE;

    int t = blockIdx.x * 128 + threadIdx.x;
    if (t >= N) return;
    int n = perm[t];
    const float* xd = x + (size_t)n * D;

    float acc[D];
#pragma unroll
    for (int j = 0; j < D; ++j) acc[j] = 0.f;

    int beg = off[n], end = off[n + 1];

    for (int i = beg; i < end; ++i) {
        const float* xs = x + (size_t)esrc[i] * D;

        // GEMM1: tmp = be1 + [xs;xd] @ We1   (k runtime -> s_load weights)
        float tmp[D];
#pragma unroll
        for (int j = 0; j < D; ++j) tmp[j] = be1[j];

#pragma unroll 1
        for (int k = 0; k < D; k += 4) {
            float4 a = *(const float4*)(xs + k);
            const float* w = We1 + k * D;
#pragma unroll
            for (int j = 0; j < D; ++j) tmp[j] += a.x * w[j];
#pragma unroll
            for (int j = 0; j < D; ++j) tmp[j] += a.y * w[j + D];
#pragma unroll
            for (int j = 0; j < D; ++j) tmp[j] += a.z * w[j + 2 * D];
#pragma unroll
            for (int j = 0; j < D; ++j) tmp[j] += a.w * w[j + 3 * D];
        }
#pragma unroll 1
        for (int k = 0; k < D; k += 4) {
            float4 a = *(const float4*)(xd + k);
            const float* w = We1 + (D + k) * D;
#pragma unroll
            for (int j = 0; j < D; ++j) tmp[j] += a.x * w[j];
#pragma unroll
            for (int j = 0; j < D; ++j) tmp[j] += a.y * w[j + D];
#pragma unroll
            for (int j = 0; j < D; ++j) tmp[j] += a.z * w[j + 2 * D];
#pragma unroll
            for (int j = 0; j < D; ++j) tmp[j] += a.w * w[j + 3 * D];
        }

        // relu, dump hidden to own LDS slice (runtime-indexable for GEMM2)
#pragma unroll
        for (int j = 0; j < D; ++j) hl[j] = fmaxf(tmp[j], 0.f);

        // GEMM2: m = be2 + h @ We2  (k runtime via LDS read, j unrolled regs)
        float m[D];
#pragma unroll
        for (int j = 0; j < D; ++j) m[j] = be2[j];
#pragma unroll 1
        for (int k = 0; k < D; ++k) {
            float h = hl[k];
            const float* w = We2 + k * D;
#pragma unroll
            for (int j = 0; j < D; ++j) m[j] += h * w[j];
        }

        // u_mul_e + accumulate in registers
#pragma unroll
        for (int j = 0; j < D; j += 4) {
            float4 xv = *(const float4*)(xs + j);
            acc[j + 0] += xv.x * m[j + 0];
            acc[j + 1] += xv.y * m[j + 1];
            acc[j + 2] += xv.z * m[j + 2];
            acc[j + 3] += xv.w * m[j + 3];
        }
    }

    float* row = hneigh + (size_t)n * D;
#pragma unroll
    for (int j = 0; j < D; j += 4) {
        float4 v;
        v.x = acc[j]; v.y = acc[j + 1]; v.z = acc[j + 2]; v.w = acc[j + 3];
        *(float4*)(row + j) = v;
    }
}

// ---------------------------------------------------------------------------
// Node MLP: h2 = relu(h_neigh @ Wn + bn) in place; gate = h2 @ Wg + bg.
// k-runtime (scalar global reads, L1-hot), j-unrolled register accumulators.
// ---------------------------------------------------------------------------
__global__ __launch_bounds__(256) void node_kernel(
    float* __restrict__ hneigh,
    const float* __restrict__ Wn, const float* __restrict__ bn,
    const float* __restrict__ Wg, const float* __restrict__ bg,
    float* __restrict__ gate, int N)
{
    int n = blockIdx.x * 256 + threadIdx.x;
    if (n >= N) return;
    float* row = hneigh + (size_t)n * D;

    float m[D];
#pragma unroll
    for (int j = 0; j < D; ++j) m[j] = bn[j];
#pragma unroll 1
    for (int k = 0; k < D; ++k) {
        float h = row[k];
        const float* w = Wn + k * D;
#pragma unroll
        for (int j = 0; j < D; ++j) m[j] += h * w[j];
    }
    float g = bg[0];
#pragma unroll
    for (int j = 0; j < D; ++j) {
        m[j] = fmaxf(m[j], 0.f);
        g += m[j] * Wg[j];
    }
#pragma unroll
    for (int j = 0; j < D; j += 4) {
        float4 v;
        v.x = m[j]; v.y = m[j + 1]; v.z = m[j + 2]; v.w = m[j + 3];
        *(float4*)(row + j) = v;
    }
    gate[n] = g;
}

// ---------------------------------------------------------------------------
// Pool: one block per graph; binary-search segment, softmax over gates,
// weighted sum, fused classifier.
// ---------------------------------------------------------------------------
__global__ __launch_bounds__(256) void pool_kernel(
    const float* __restrict__ h2,
    const float* __restrict__ gate,
    const int* __restrict__ gid,
    const float* __restrict__ Wfc, const float* __restrict__ bfc,
    float* __restrict__ out, int N, int C)
{
    int g = blockIdx.x;
    int tid = threadIdx.x;

    int lo = 0, hi = N;
    while (lo < hi) { int mid = (lo + hi) >> 1; if (gid[mid] < g) lo = mid + 1; else hi = mid; }
    int s = lo;
    hi = N;
    while (lo < hi) { int mid = (lo + hi) >> 1; if (gid[mid] < g + 1) lo = mid + 1; else hi = mid; }
    int e = lo;

    __shared__ float red[256];
    __shared__ float accs[4][D];
    __shared__ float dens[4];

    float m = -INFINITY;
    for (int i = s + tid; i < e; i += 256) m = fmaxf(m, gate[i]);
    red[tid] = m;
    __syncthreads();
    for (int w = 128; w > 0; w >>= 1) {
        if (tid < w) red[tid] = fmaxf(red[tid], red[tid + w]);
        __syncthreads();
    }
    float gmax = red[0];
    __syncthreads();

    int f = tid & (D - 1);
    int grp = tid >> 6;
    float acc = 0.0f, den = 0.0f;
    for (int i = s + grp; i < e; i += 4) {
        float w = expf(gate[i] - gmax);
        acc += w * h2[(size_t)i * D + f];
        if (f == 0) den += w;
    }
    accs[grp][f] = acc;
    if (f == 0) dens[grp] = den;
    __syncthreads();

    if (tid < D) {
        float p = accs[0][tid] + accs[1][tid] + accs[2][tid] + accs[3][tid];
        float dn = dens[0] + dens[1] + dens[2] + dens[3];
        p = (e > s) ? (p / dn) : 0.0f;
        red[tid] = p;
    }
    __syncthreads();

    if (tid < C) {
        float o = bfc[tid];
#pragma unroll
        for (int k = 0; k < D; ++k) o += red[k] * Wfc[k * C + tid];
        out[g * C + tid] = o;
    }
}

extern "C" void kernel_launch(void* const* d_in, const int* in_sizes, int n_in,
                              void* d_out, int out_size, void* d_ws, size_t ws_size,
                              hipStream_t stream) {
    const float* x   = (const float*)d_in[0];
    const float* We1 = (const float*)d_in[1];
    const float* be1 = (const float*)d_in[2];
    const float* We2 = (const float*)d_in[3];
    const float* be2 = (const float*)d_in[4];
    const float* Wn  = (const float*)d_in[5];
    const float* bn  = (const float*)d_in[6];
    const float* Wg  = (const float*)d_in[7];
    const float* bg  = (const float*)d_in[8];
    const float* Wfc = (const float*)d_in[9];
    const float* bfc = (const float*)d_in[10];
    const int* src = (const int*)d_in[11];
    const int* dst = (const int*)d_in[12];
    const int* gid = (const int*)d_in[13];

    const int N = in_sizes[0] / D;
    const int E = in_sizes[11];
    const int C = 10;
    const int G = out_size / C;

    float* hneigh = (float*)d_ws;                      // [N*D]
    float* gate   = hneigh + (size_t)N * D;            // [N]
    int*   deg    = (int*)(gate + N);                  // [N]
    int*   dhist  = deg + N;                           // [256]
    int*   dcur   = dhist + 256;                       // [256]
    int*   off    = dcur + 256;                        // [N+1]
    int*   cursor = off + N + 1;                       // [N]
    int*   perm   = cursor + N;                        // [N]
    int*   esrc   = perm + N;                          // [E]
    float* outp   = (float*)d_out;

    // zero deg + dhist in one shot (adjacent)
    hipMemsetAsync(deg, 0, ((size_t)N + 256) * sizeof(int), stream);

    hist_kernel<<<(E + 255) / 256, 256, 0, stream>>>(dst, deg, E);
    scan_kernel<<<1, 1024, 0, stream>>>(deg, off, cursor, N);
    fill_kernel<<<(E + 255) / 256, 256, 0, stream>>>(dst, src, cursor, esrc, E);
    dhist_kernel<<<(N + 255) / 256, 256, 0, stream>>>(deg, dhist, N);
    dscan_kernel<<<1, 256, 0, stream>>>(dhist, dcur);
    dscatter_kernel<<<(N + 255) / 256, 256, 0, stream>>>(deg, dcur, perm, N);

    gather_edge_kernel<<<(N + 127) / 128, 128, 0, stream>>>(
        x, We1, be1, We2, be2, off, esrc, perm, hneigh, N);
    node_kernel<<<(N + 255) / 256, 256, 0, stream>>>(hneigh, Wn, bn, Wg, bg, gate, N);
    pool_kernel<<<G, 256, 0, stream>>>(hneigh, gate, gid, Wfc, bfc, outp, N, C);
}

// Round 4
// 1029.428 us; speedup vs baseline: 5.3563x; 2.9305x over previous
//
#include <hip/hip_runtime.h>
#include <hip/hip_bf16.h>

#define D 64

typedef _Float16 f16;
typedef _Float16 f16x4 __attribute__((ext_vector_type(4)));
typedef _Float16 f16x8 __attribute__((ext_vector_type(8)));
typedef float f32x4 __attribute__((ext_vector_type(4)));

// XOR-swizzled f16 index (16B-chunk swizzle): conflict-free b128 frag reads,
// no row padding (keeps 16B alignment for f16x8 loads).
__device__ __forceinline__ int sw7(int m, int k) {  // row stride 128 f16
    return (m << 7) + (((k >> 3) ^ (m & 7)) << 3) + (k & 7);
}
__device__ __forceinline__ int sw6(int m, int k) {  // row stride 64 f16
    return (m << 6) + ((((k >> 3) ^ (m & 7)) & 7) << 3) + (k & 7);
}

// ---------------------------------------------------------------------------
// CSR build: histogram, hierarchical scan, fill (src grouped by dst).
// ---------------------------------------------------------------------------
__global__ void hist_kernel(const int* __restrict__ dst, int* __restrict__ deg, int E)
{
    int e = blockIdx.x * 256 + threadIdx.x;
    if (e < E) atomicAdd(&deg[dst[e]], 1);
}

__global__ void scan_part(const int* __restrict__ deg, int* __restrict__ part, int N)
{
    __shared__ int red[256];
    int b = blockIdx.x, t = threadIdx.x;
    int base = b * 1024 + t * 4;
    int s = 0;
#pragma unroll
    for (int u = 0; u < 4; ++u) { int i = base + u; if (i < N) s += deg[i]; }
    red[t] = s; __syncthreads();
    for (int w = 128; w > 0; w >>= 1) {
        if (t < w) red[t] += red[t + w];
        __syncthreads();
    }
    if (t == 0) part[b] = red[0];
}

__global__ void scan_mid(int* __restrict__ part, int* __restrict__ offN, int B)
{
    if (threadIdx.x == 0) {
        int run = 0;
        for (int b = 0; b < B; ++b) { int v = part[b]; part[b] = run; run += v; }
        *offN = run;  // off[N] = E
    }
}

__global__ void scan_out(const int* __restrict__ deg, const int* __restrict__ part,
                         int* __restrict__ off, int* __restrict__ cursor, int N)
{
    __shared__ int lds[256];
    int b = blockIdx.x, t = threadIdx.x;
    int base = b * 1024 + t * 4;
    int dv[4]; int s = 0;
#pragma unroll
    for (int u = 0; u < 4; ++u) { int i = base + u; dv[u] = (i < N) ? deg[i] : 0; s += dv[u]; }
    lds[t] = s; __syncthreads();
    for (int d2 = 1; d2 < 256; d2 <<= 1) {
        int v = (t >= d2) ? lds[t - d2] : 0;
        __syncthreads();
        lds[t] += v;
        __syncthreads();
    }
    int run = part[b] + lds[t] - s;  // exclusive prefix
#pragma unroll
    for (int u = 0; u < 4; ++u) {
        int i = base + u;
        if (i < N) { off[i] = run; cursor[i] = run; }
        run += dv[u];
    }
}

__global__ void fill_kernel(const int* __restrict__ dst, const int* __restrict__ src,
                            int* __restrict__ cursor, int* __restrict__ esrc, int E)
{
    int e = blockIdx.x * 256 + threadIdx.x;
    if (e < E) {
        int p = atomicAdd(&cursor[dst[e]], 1);
        esrc[p] = src[e];
    }
}

// ---------------------------------------------------------------------------
// Edge MLP via MFMA (f16 split precision), fused u_mul_e + segmented sum.
// Tile = 32 sorted edges. Weights LDS-resident (staged once per block).
// GEMM1 3-term split (hi*hi + hi*lo + lo*hi); GEMM2 single-f16 (err ~1e-4).
// ---------------------------------------------------------------------------
__global__ __launch_bounds__(256, 2) void edge_mfma_kernel(
    const float* __restrict__ x,
    const float* __restrict__ We1, const float* __restrict__ be1,
    const float* __restrict__ We2, const float* __restrict__ be2,
    const int* __restrict__ off, const int* __restrict__ esrc,
    float* __restrict__ hneigh, int N, int E, int T)
{
    __shared__ __attribute__((aligned(16))) f16 W1hi[64 * 128];
    __shared__ __attribute__((aligned(16))) f16 W1lo[64 * 128];
    __shared__ __attribute__((aligned(16))) f16 W2hi[64 * 64];
    __shared__ __attribute__((aligned(16))) f16 Abuf[2 * 32 * 128]; // Ahi|Alo; contrib overlays
    __shared__ __attribute__((aligned(16))) f16 Hbuf[32 * 64];      // hid hi; edst scratch early

    f16* Ahi = Abuf;
    f16* Alo = Abuf + 32 * 128;
    float* Contrib = (float*)Abuf;     // [32][64] f32, written after xs->regs
    int* edstS = (int*)Hbuf;           // 32 ints, used only during staging

    const int tid = threadIdx.x;

    // ---- stage weights once ----
    {
        int n = tid & 63;
        int kb = (tid >> 6) * 32;
        for (int kk = 0; kk < 32; ++kk) {
            int k = kb + kk;
            float v = We1[k * 64 + n];
            f16 h = (f16)v;
            W1hi[sw7(n, k)] = h;
            W1lo[sw7(n, k)] = (f16)(v - (float)h);
        }
        int kb2 = (tid >> 6) * 16;
        for (int kk = 0; kk < 16; ++kk) {
            int k = kb2 + kk;
            W2hi[sw6(n, k)] = (f16)We2[k * 64 + n];
        }
    }

    const int w = tid >> 6;
    const int lane = tid & 63;
    const int l15 = lane & 15;
    const int quad = lane >> 4;
    const int m0 = (w & 1) * 16;        // edge strip within tile
    const int nh = (w >> 1) * 32;       // feature half

    const float b1v0 = be1[nh + l15],      b1v1 = be1[nh + 16 + l15];
    const float b2v0 = be2[nh + l15],      b2v1 = be2[nh + 16 + l15];

    __syncthreads();

    for (int tile = blockIdx.x; tile < T; tile += gridDim.x) {
        const int e0 = tile * 32;
        const int etile = min(32, E - e0);

        // ---- find dst node of each edge (sorted order -> search off) ----
        if (tid < 32) {
            int ei = min(e0 + tid, E - 1);
            int lo = 0, hi = N + 1;
            while (lo < hi) { int mid = (lo + hi) >> 1; if (off[mid] <= ei) lo = mid + 1; else hi = mid; }
            edstS[tid] = lo - 1;
        }
        __syncthreads();

        // ---- gather + f16-split A: [32 edges][128] = [x_src | x_dst] ----
        {
            int i = tid >> 3;                 // edge in tile
            int q = tid & 7;                  // 16-feature quarter
            int ei = min(e0 + i, E - 1);
            int node = (q < 4) ? esrc[ei] : edstS[i];
            const float* p = x + (size_t)node * D + (q & 3) * 16;
            int kbase = (q & 3) * 16 + ((q < 4) ? 0 : 64);
#pragma unroll
            for (int r = 0; r < 4; ++r) {
                float4 v = *(const float4*)(p + r * 4);
                int k = kbase + r * 4;
                f16x4 hv, lv;
                hv[0] = (f16)v.x; lv[0] = (f16)(v.x - (float)hv[0]);
                hv[1] = (f16)v.y; lv[1] = (f16)(v.y - (float)hv[1]);
                hv[2] = (f16)v.z; lv[2] = (f16)(v.z - (float)hv[2]);
                hv[3] = (f16)v.w; lv[3] = (f16)(v.w - (float)hv[3]);
                *(f16x4*)&Ahi[sw7(i, k)] = hv;
                *(f16x4*)&Alo[sw7(i, k)] = lv;
            }
        }
        __syncthreads();

        // ---- GEMM1: [32,128]@[128,64], 3-term split ----
        f32x4 c0 = {0.f, 0.f, 0.f, 0.f}, c1 = {0.f, 0.f, 0.f, 0.f};
#pragma unroll
        for (int kt = 0; kt < 4; ++kt) {
            int k = kt * 32 + quad * 8;
            f16x8 ah = *(const f16x8*)&Ahi[sw7(m0 + l15, k)];
            f16x8 al = *(const f16x8*)&Alo[sw7(m0 + l15, k)];
            f16x8 b0h = *(const f16x8*)&W1hi[sw7(nh + l15, k)];
            f16x8 b0l = *(const f16x8*)&W1lo[sw7(nh + l15, k)];
            f16x8 b1h = *(const f16x8*)&W1hi[sw7(nh + 16 + l15, k)];
            f16x8 b1l = *(const f16x8*)&W1lo[sw7(nh + 16 + l15, k)];
            c0 = __builtin_amdgcn_mfma_f32_16x16x32_f16(ah, b0h, c0, 0, 0, 0);
            c0 = __builtin_amdgcn_mfma_f32_16x16x32_f16(ah, b0l, c0, 0, 0, 0);
            c0 = __builtin_amdgcn_mfma_f32_16x16x32_f16(al, b0h, c0, 0, 0, 0);
            c1 = __builtin_amdgcn_mfma_f32_16x16x32_f16(ah, b1h, c1, 0, 0, 0);
            c1 = __builtin_amdgcn_mfma_f32_16x16x32_f16(ah, b1l, c1, 0, 0, 0);
            c1 = __builtin_amdgcn_mfma_f32_16x16x32_f16(al, b1h, c1, 0, 0, 0);
        }
        __syncthreads();   // edstS scratch dead; Hbuf becomes hid

        // relu + f16, C-layout -> LDS (A-layout for GEMM2)
#pragma unroll
        for (int i2 = 0; i2 < 4; ++i2) {
            int m = m0 + quad * 4 + i2;
            float v0 = fmaxf(c0[i2] + b1v0, 0.f);
            float v1 = fmaxf(c1[i2] + b1v1, 0.f);
            Hbuf[sw6(m, nh + l15)] = (f16)v0;
            Hbuf[sw6(m, nh + 16 + l15)] = (f16)v1;
        }
        __syncthreads();

        // ---- GEMM2: [32,64]@[64,64], single-f16 ----
        f32x4 d0 = {0.f, 0.f, 0.f, 0.f}, d1 = {0.f, 0.f, 0.f, 0.f};
#pragma unroll
        for (int kt = 0; kt < 2; ++kt) {
            int k = kt * 32 + quad * 8;
            f16x8 ah = *(const f16x8*)&Hbuf[sw6(m0 + l15, k)];
            f16x8 b0 = *(const f16x8*)&W2hi[sw6(nh + l15, k)];
            f16x8 b1 = *(const f16x8*)&W2hi[sw6(nh + 16 + l15, k)];
            d0 = __builtin_amdgcn_mfma_f32_16x16x32_f16(ah, b0, d0, 0, 0, 0);
            d1 = __builtin_amdgcn_mfma_f32_16x16x32_f16(ah, b1, d1, 0, 0, 0);
        }

        // xs = x[src][j] reconstructed from A hi+lo, into regs before overlay
        float xs0[4], xs1[4];
#pragma unroll
        for (int i2 = 0; i2 < 4; ++i2) {
            int m = m0 + quad * 4 + i2;
            xs0[i2] = (float)Ahi[sw7(m, nh + l15)] + (float)Alo[sw7(m, nh + l15)];
            xs1[i2] = (float)Ahi[sw7(m, nh + 16 + l15)] + (float)Alo[sw7(m, nh + 16 + l15)];
        }
        __syncthreads();

        // contrib = xs * (d + be2), overlaying A region
#pragma unroll
        for (int i2 = 0; i2 < 4; ++i2) {
            int m = m0 + quad * 4 + i2;
            Contrib[m * 64 + nh + l15]      = (d0[i2] + b2v0) * xs0[i2];
            Contrib[m * 64 + nh + 16 + l15] = (d1[i2] + b2v1) * xs1[i2];
        }
        __syncthreads();

        // ---- segmented sum over sorted dst runs (thread j = feature) ----
        if (tid < 64) {
            int j = tid;
            int lo = 0, hi = N + 1;
            while (lo < hi) { int mid = (lo + hi) >> 1; if (off[mid] <= e0) lo = mid + 1; else hi = mid; }
            int d = lo - 1;
            int i = 0;
            while (i < etile) {
                int segend = min(off[d + 1] - e0, etile);
                if (segend > i) {
                    float a = 0.f;
                    for (int ii = i; ii < segend; ++ii) a += Contrib[ii * 64 + j];
                    if (off[d] >= e0 && off[d + 1] <= e0 + etile)
                        hneigh[(size_t)d * D + j] = a;          // complete run
                    else
                        atomicAdd(&hneigh[(size_t)d * D + j], a); // tile-crossing run
                    i = segend;
                }
                ++d;
            }
        }
        __syncthreads();   // protect A/H reuse next tile
    }
}

// ---------------------------------------------------------------------------
// Node MLP via MFMA: h2 = relu(h @ Wn + bn) in place; gate = h2 @ Wg + bg.
// Tile = 64 nodes (contiguous rows, no gather). 3-term split.
// ---------------------------------------------------------------------------
__global__ __launch_bounds__(256, 2) void node_mfma_kernel(
    float* __restrict__ h,     // [N,D] in: h_neigh, out: h2
    const float* __restrict__ Wn, const float* __restrict__ bn,
    const float* __restrict__ Wg, const float* __restrict__ bg,
    float* __restrict__ gate, int N, int T)
{
    __shared__ __attribute__((aligned(16))) f16 WNhi[64 * 64];
    __shared__ __attribute__((aligned(16))) f16 WNlo[64 * 64];
    __shared__ __attribute__((aligned(16))) f16 ANhi[64 * 64];
    __shared__ __attribute__((aligned(16))) f16 ANlo[64 * 64];

    const int tid = threadIdx.x;
    {
        int n = tid & 63;
        int kb = (tid >> 6) * 16;
        for (int kk = 0; kk < 16; ++kk) {
            int k = kb + kk;
            float v = Wn[k * 64 + n];
            f16 hh = (f16)v;
            WNhi[sw6(n, k)] = hh;
            WNlo[sw6(n, k)] = (f16)(v - (float)hh);
        }
    }

    const int w = tid >> 6;
    const int lane = tid & 63;
    const int l15 = lane & 15;
    const int quad = lane >> 4;
    const int m0 = w * 16;

    float bnv[4], wgv[4];
#pragma unroll
    for (int nt = 0; nt < 4; ++nt) {
        bnv[nt] = bn[nt * 16 + l15];
        wgv[nt] = Wg[nt * 16 + l15];
    }
    const float bgv = bg[0];

    __syncthreads();

    for (int tile = blockIdx.x; tile < T; tile += gridDim.x) {
        const int t0 = tile * 64;

        // stage 64 node rows (clamped), f16 split
        {
            int i = tid >> 2;
            int q = tid & 3;
            int node = min(t0 + i, N - 1);
            const float* p = h + (size_t)node * D + q * 16;
#pragma unroll
            for (int r = 0; r < 4; ++r) {
                float4 v = *(const float4*)(p + r * 4);
                int k = q * 16 + r * 4;
                f16x4 hv, lv;
                hv[0] = (f16)v.x; lv[0] = (f16)(v.x - (float)hv[0]);
                hv[1] = (f16)v.y; lv[1] = (f16)(v.y - (float)hv[1]);
                hv[2] = (f16)v.z; lv[2] = (f16)(v.z - (float)hv[2]);
                hv[3] = (f16)v.w; lv[3] = (f16)(v.w - (float)hv[3]);
                *(f16x4*)&ANhi[sw6(i, k)] = hv;
                *(f16x4*)&ANlo[sw6(i, k)] = lv;
            }
        }
        __syncthreads();

        f32x4 c[4] = {{0.f,0.f,0.f,0.f},{0.f,0.f,0.f,0.f},{0.f,0.f,0.f,0.f},{0.f,0.f,0.f,0.f}};
#pragma unroll
        for (int kt = 0; kt < 2; ++kt) {
            int k = kt * 32 + quad * 8;
            f16x8 ah = *(const f16x8*)&ANhi[sw6(m0 + l15, k)];
            f16x8 al = *(const f16x8*)&ANlo[sw6(m0 + l15, k)];
#pragma unroll
            for (int nt = 0; nt < 4; ++nt) {
                f16x8 bh = *(const f16x8*)&WNhi[sw6(nt * 16 + l15, k)];
                f16x8 bl = *(const f16x8*)&WNlo[sw6(nt * 16 + l15, k)];
                c[nt] = __builtin_amdgcn_mfma_f32_16x16x32_f16(ah, bh, c[nt], 0, 0, 0);
                c[nt] = __builtin_amdgcn_mfma_f32_16x16x32_f16(ah, bl, c[nt], 0, 0, 0);
                c[nt] = __builtin_amdgcn_mfma_f32_16x16x32_f16(al, bh, c[nt], 0, 0, 0);
            }
        }
        __syncthreads();   // staging buffers reusable next iter after epilogue

        float gpart[4] = {0.f, 0.f, 0.f, 0.f};
#pragma unroll
        for (int nt = 0; nt < 4; ++nt) {
            int n = nt * 16 + l15;
#pragma unroll
            for (int i2 = 0; i2 < 4; ++i2) {
                int m = t0 + m0 + quad * 4 + i2;
                float v = fmaxf(c[nt][i2] + bnv[nt], 0.f);
                if (m < N) h[(size_t)m * D + n] = v;
                gpart[i2] += v * wgv[nt];
            }
        }
#pragma unroll
        for (int s = 1; s < 16; s <<= 1) {
#pragma unroll
            for (int i2 = 0; i2 < 4; ++i2) gpart[i2] += __shfl_xor(gpart[i2], s);
        }
        if (l15 == 0) {
#pragma unroll
            for (int i2 = 0; i2 < 4; ++i2) {
                int m = t0 + m0 + quad * 4 + i2;
                if (m < N) gate[m] = gpart[i2] + bgv;
            }
        }
        __syncthreads();
    }
}

// ---------------------------------------------------------------------------
// Pool: one block per graph; softmax over gates, weighted sum, classifier.
// ---------------------------------------------------------------------------
__global__ __launch_bounds__(256) void pool_kernel(
    const float* __restrict__ h2,
    const float* __restrict__ gate,
    const int* __restrict__ gid,
    const float* __restrict__ Wfc, const float* __restrict__ bfc,
    float* __restrict__ out, int N, int C)
{
    int g = blockIdx.x;
    int tid = threadIdx.x;

    int lo = 0, hi = N;
    while (lo < hi) { int mid = (lo + hi) >> 1; if (gid[mid] < g) lo = mid + 1; else hi = mid; }
    int s = lo;
    hi = N;
    while (lo < hi) { int mid = (lo + hi) >> 1; if (gid[mid] < g + 1) lo = mid + 1; else hi = mid; }
    int e = lo;

    __shared__ float red[256];
    __shared__ float accs[4][D];
    __shared__ float dens[4];

    float m = -INFINITY;
    for (int i = s + tid; i < e; i += 256) m = fmaxf(m, gate[i]);
    red[tid] = m;
    __syncthreads();
    for (int w = 128; w > 0; w >>= 1) {
        if (tid < w) red[tid] = fmaxf(red[tid], red[tid + w]);
        __syncthreads();
    }
    float gmax = red[0];
    __syncthreads();

    int f = tid & (D - 1);
    int grp = tid >> 6;
    float acc = 0.0f, den = 0.0f;
    for (int i = s + grp; i < e; i += 4) {
        float w = expf(gate[i] - gmax);
        acc += w * h2[(size_t)i * D + f];
        if (f == 0) den += w;
    }
    accs[grp][f] = acc;
    if (f == 0) dens[grp] = den;
    __syncthreads();

    if (tid < D) {
        float p = accs[0][tid] + accs[1][tid] + accs[2][tid] + accs[3][tid];
        float dn = dens[0] + dens[1] + dens[2] + dens[3];
        p = (e > s) ? (p / dn) : 0.0f;
        red[tid] = p;
    }
    __syncthreads();

    if (tid < C) {
        float o = bfc[tid];
#pragma unroll
        for (int k = 0; k < D; ++k) o += red[k] * Wfc[k * C + tid];
        out[g * C + tid] = o;
    }
}

extern "C" void kernel_launch(void* const* d_in, const int* in_sizes, int n_in,
                              void* d_out, int out_size, void* d_ws, size_t ws_size,
                              hipStream_t stream) {
    const float* x   = (const float*)d_in[0];
    const float* We1 = (const float*)d_in[1];
    const float* be1 = (const float*)d_in[2];
    const float* We2 = (const float*)d_in[3];
    const float* be2 = (const float*)d_in[4];
    const float* Wn  = (const float*)d_in[5];
    const float* bn  = (const float*)d_in[6];
    const float* Wg  = (const float*)d_in[7];
    const float* bg  = (const float*)d_in[8];
    const float* Wfc = (const float*)d_in[9];
    const float* bfc = (const float*)d_in[10];
    const int* src = (const int*)d_in[11];
    const int* dst = (const int*)d_in[12];
    const int* gid = (const int*)d_in[13];

    const int N = in_sizes[0] / D;
    const int E = in_sizes[11];
    const int C = 10;
    const int G = out_size / C;

    float* hneigh = (float*)d_ws;                 // [N*D]
    float* gate   = hneigh + (size_t)N * D;       // [N]
    int*   deg    = (int*)(gate + N);             // [N]
    int*   off    = deg + N;                      // [N+1]
    int*   cursor = off + N + 1;                  // [N]
    int*   part   = cursor + N;                   // [128]
    int*   esrc   = part + 128;                   // [E]
    float* outp   = (float*)d_out;

    const int Bp = (N + 1023) / 1024;
    const int Te = (E + 31) / 32;
    const int Tn = (N + 63) / 64;

    hipMemsetAsync(hneigh, 0, (size_t)N * D * sizeof(float), stream);
    hipMemsetAsync(deg, 0, (size_t)N * sizeof(int), stream);

    hist_kernel<<<(E + 255) / 256, 256, 0, stream>>>(dst, deg, E);
    scan_part<<<Bp, 256, 0, stream>>>(deg, part, N);
    scan_mid<<<1, 64, 0, stream>>>(part, off + N, Bp);
    scan_out<<<Bp, 256, 0, stream>>>(deg, part, off, cursor, N);
    fill_kernel<<<(E + 255) / 256, 256, 0, stream>>>(dst, src, cursor, esrc, E);

    edge_mfma_kernel<<<512, 256, 0, stream>>>(x, We1, be1, We2, be2,
                                              off, esrc, hneigh, N, E, Te);
    node_mfma_kernel<<<1024, 256, 0, stream>>>(hneigh, Wn, bn, Wg, bg, gate, N, Tn);
    pool_kernel<<<G, 256, 0, stream>>>(hneigh, gate, gid, Wfc, bfc, outp, N, C);
}

// Round 5
// 890.600 us; speedup vs baseline: 6.1912x; 1.1559x over previous
//
#include <hip/hip_runtime.h>
#include <hip/hip_bf16.h>

#define D 64

typedef _Float16 f16;
typedef _Float16 f16x4 __attribute__((ext_vector_type(4)));
typedef _Float16 f16x8 __attribute__((ext_vector_type(8)));
typedef float f32x4 __attribute__((ext_vector_type(4)));

// XOR-swizzled f16 index (16B-chunk swizzle): conflict-free b128 frag reads,
// no row padding (keeps 16B alignment for f16x8 loads).
__device__ __forceinline__ int sw7(int m, int k) {  // row stride 128 f16
    return (m << 7) + (((k >> 3) ^ (m & 7)) << 3) + (k & 7);
}
__device__ __forceinline__ int sw6(int m, int k) {  // row stride 64 f16
    return (m << 6) + ((((k >> 3) ^ (m & 7)) & 7) << 3) + (k & 7);
}

// ---------------------------------------------------------------------------
// CSR build: histogram, hierarchical scan, fill (src + dst grouped by dst).
// ---------------------------------------------------------------------------
__global__ void hist_kernel(const int* __restrict__ dst, int* __restrict__ deg, int E)
{
    int e = blockIdx.x * 256 + threadIdx.x;
    if (e < E) atomicAdd(&deg[dst[e]], 1);
}

__global__ void scan_part(const int* __restrict__ deg, int* __restrict__ part, int N)
{
    __shared__ int red[256];
    int b = blockIdx.x, t = threadIdx.x;
    int base = b * 1024 + t * 4;
    int s = 0;
#pragma unroll
    for (int u = 0; u < 4; ++u) { int i = base + u; if (i < N) s += deg[i]; }
    red[t] = s; __syncthreads();
    for (int w = 128; w > 0; w >>= 1) {
        if (t < w) red[t] += red[t + w];
        __syncthreads();
    }
    if (t == 0) part[b] = red[0];
}

__global__ void scan_mid(int* __restrict__ part, int* __restrict__ offN, int B)
{
    if (threadIdx.x == 0) {
        int run = 0;
        for (int b = 0; b < B; ++b) { int v = part[b]; part[b] = run; run += v; }
        *offN = run;  // off[N] = E
    }
}

__global__ void scan_out(const int* __restrict__ deg, const int* __restrict__ part,
                         int* __restrict__ off, int* __restrict__ cursor, int N)
{
    __shared__ int lds[256];
    int b = blockIdx.x, t = threadIdx.x;
    int base = b * 1024 + t * 4;
    int dv[4]; int s = 0;
#pragma unroll
    for (int u = 0; u < 4; ++u) { int i = base + u; dv[u] = (i < N) ? deg[i] : 0; s += dv[u]; }
    lds[t] = s; __syncthreads();
    for (int d2 = 1; d2 < 256; d2 <<= 1) {
        int v = (t >= d2) ? lds[t - d2] : 0;
        __syncthreads();
        lds[t] += v;
        __syncthreads();
    }
    int run = part[b] + lds[t] - s;  // exclusive prefix
#pragma unroll
    for (int u = 0; u < 4; ++u) {
        int i = base + u;
        if (i < N) { off[i] = run; cursor[i] = run; }
        run += dv[u];
    }
}

__global__ void fill_kernel(const int* __restrict__ dst, const int* __restrict__ src,
                            int* __restrict__ cursor, int* __restrict__ esrc,
                            int* __restrict__ edstg, int E)
{
    int e = blockIdx.x * 256 + threadIdx.x;
    if (e < E) {
        int d = dst[e];
        int p = atomicAdd(&cursor[d], 1);
        esrc[p] = src[e];
        edstg[p] = d;
    }
}

// ---------------------------------------------------------------------------
// Edge MLP via MFMA (f16 split precision), fused u_mul_e + segmented sum.
// Tile = 32 sorted edges. Weights LDS-resident. No per-tile binary searches:
// edstg[] gives each edge's dst; two prefetched off[] scalars classify runs.
// ---------------------------------------------------------------------------
__global__ __launch_bounds__(256, 2) void edge_mfma_kernel(
    const float* __restrict__ x,
    const float* __restrict__ We1, const float* __restrict__ be1,
    const float* __restrict__ We2, const float* __restrict__ be2,
    const int* __restrict__ off, const int* __restrict__ esrc,
    const int* __restrict__ edstg,
    float* __restrict__ hneigh, int N, int E, int T)
{
    __shared__ __attribute__((aligned(16))) f16 W1hi[64 * 128];   // 16KB
    __shared__ __attribute__((aligned(16))) f16 W1lo[64 * 128];   // 16KB
    __shared__ __attribute__((aligned(16))) f16 W2hi[64 * 64];    // 8KB
    __shared__ __attribute__((aligned(16))) f16 Abuf[2 * 32 * 128]; // 16KB; Contrib overlays
    __shared__ __attribute__((aligned(16))) f16 Hbuf[32 * 64];    // 4KB
    __shared__ int edstS[32];
    __shared__ int offFS_, offLS_;

    f16* Ahi = Abuf;
    f16* Alo = Abuf + 32 * 128;
    float* Contrib = (float*)Abuf;     // [32][65] f32 (8.3KB), after xs->regs

    const int tid = threadIdx.x;

    // ---- stage weights once ----
    {
        int n = tid & 63;
        int kb = (tid >> 6) * 32;
        for (int kk = 0; kk < 32; ++kk) {
            int k = kb + kk;
            float v = We1[k * 64 + n];
            f16 h = (f16)v;
            W1hi[sw7(n, k)] = h;
            W1lo[sw7(n, k)] = (f16)(v - (float)h);
        }
        int kb2 = (tid >> 6) * 16;
        for (int kk = 0; kk < 16; ++kk) {
            int k = kb2 + kk;
            W2hi[sw6(n, k)] = (f16)We2[k * 64 + n];
        }
    }

    const int w = tid >> 6;
    const int lane = tid & 63;
    const int l15 = lane & 15;
    const int quad = lane >> 4;
    const int m0 = (w & 1) * 16;        // edge strip within tile
    const int nh = (w >> 1) * 32;       // feature half

    const float b1v0 = be1[nh + l15],      b1v1 = be1[nh + 16 + l15];
    const float b2v0 = be2[nh + l15],      b2v1 = be2[nh + 16 + l15];

    __syncthreads();

    for (int tile = blockIdx.x; tile < T; tile += gridDim.x) {
        const int e0 = tile * 32;
        const int etile = min(32, E - e0);

        // ---- stage A: thread = (edge i, chunk pair c/c+8), b128 writes ----
        {
            int i = tid >> 3;                 // edge in tile
            int c = tid & 7;                  // 8-feature chunk
            int ei = min(e0 + i, E - 1);
            int ns = esrc[ei];
            int nd = edstg[ei];
            if (tid < 32) edstS[tid] = edstg[min(e0 + tid, E - 1)];
            if (tid == 0) offFS_ = off[edstg[e0]];
            if (tid == 1) offLS_ = off[edstg[min(e0 + etile - 1, E - 1)] + 1];

            const float* ps = x + (size_t)ns * D + c * 8;
            const float* pd = x + (size_t)nd * D + c * 8;
            float4 sa = *(const float4*)(ps);
            float4 sb = *(const float4*)(ps + 4);
            float4 da = *(const float4*)(pd);
            float4 db = *(const float4*)(pd + 4);

            f16x8 sh, sl, dh, dl;
            float sv[8] = {sa.x, sa.y, sa.z, sa.w, sb.x, sb.y, sb.z, sb.w};
            float dv[8] = {da.x, da.y, da.z, da.w, db.x, db.y, db.z, db.w};
#pragma unroll
            for (int r = 0; r < 8; ++r) {
                sh[r] = (f16)sv[r]; sl[r] = (f16)(sv[r] - (float)sh[r]);
                dh[r] = (f16)dv[r]; dl[r] = (f16)(dv[r] - (float)dh[r]);
            }
            *(f16x8*)&Ahi[sw7(i, c * 8)] = sh;
            *(f16x8*)&Alo[sw7(i, c * 8)] = sl;
            *(f16x8*)&Ahi[sw7(i, 64 + c * 8)] = dh;
            *(f16x8*)&Alo[sw7(i, 64 + c * 8)] = dl;
        }
        __syncthreads();  // (1)

        // ---- GEMM1: [32,128]@[128,64], 3-term split ----
        f32x4 c0 = {0.f, 0.f, 0.f, 0.f}, c1 = {0.f, 0.f, 0.f, 0.f};
#pragma unroll
        for (int kt = 0; kt < 4; ++kt) {
            int k = kt * 32 + quad * 8;
            f16x8 ah = *(const f16x8*)&Ahi[sw7(m0 + l15, k)];
            f16x8 al = *(const f16x8*)&Alo[sw7(m0 + l15, k)];
            f16x8 b0h = *(const f16x8*)&W1hi[sw7(nh + l15, k)];
            f16x8 b0l = *(const f16x8*)&W1lo[sw7(nh + l15, k)];
            f16x8 b1h = *(const f16x8*)&W1hi[sw7(nh + 16 + l15, k)];
            f16x8 b1l = *(const f16x8*)&W1lo[sw7(nh + 16 + l15, k)];
            c0 = __builtin_amdgcn_mfma_f32_16x16x32_f16(ah, b0h, c0, 0, 0, 0);
            c0 = __builtin_amdgcn_mfma_f32_16x16x32_f16(ah, b0l, c0, 0, 0, 0);
            c0 = __builtin_amdgcn_mfma_f32_16x16x32_f16(al, b0h, c0, 0, 0, 0);
            c1 = __builtin_amdgcn_mfma_f32_16x16x32_f16(ah, b1h, c1, 0, 0, 0);
            c1 = __builtin_amdgcn_mfma_f32_16x16x32_f16(ah, b1l, c1, 0, 0, 0);
            c1 = __builtin_amdgcn_mfma_f32_16x16x32_f16(al, b1h, c1, 0, 0, 0);
        }

        // relu + f16, C-layout -> LDS (A-layout for GEMM2)
#pragma unroll
        for (int i2 = 0; i2 < 4; ++i2) {
            int m = m0 + quad * 4 + i2;
            float v0 = fmaxf(c0[i2] + b1v0, 0.f);
            float v1 = fmaxf(c1[i2] + b1v1, 0.f);
            Hbuf[sw6(m, nh + l15)] = (f16)v0;
            Hbuf[sw6(m, nh + 16 + l15)] = (f16)v1;
        }
        __syncthreads();  // (2) Hbuf writes visible

        // ---- GEMM2: [32,64]@[64,64], single-f16 ----
        f32x4 d0 = {0.f, 0.f, 0.f, 0.f}, d1 = {0.f, 0.f, 0.f, 0.f};
#pragma unroll
        for (int kt = 0; kt < 2; ++kt) {
            int k = kt * 32 + quad * 8;
            f16x8 ah = *(const f16x8*)&Hbuf[sw6(m0 + l15, k)];
            f16x8 b0 = *(const f16x8*)&W2hi[sw6(nh + l15, k)];
            f16x8 b1 = *(const f16x8*)&W2hi[sw6(nh + 16 + l15, k)];
            d0 = __builtin_amdgcn_mfma_f32_16x16x32_f16(ah, b0, d0, 0, 0, 0);
            d1 = __builtin_amdgcn_mfma_f32_16x16x32_f16(ah, b1, d1, 0, 0, 0);
        }

        // xs = x[src][j] reconstructed from A hi+lo, into regs before overlay
        float xs0[4], xs1[4];
#pragma unroll
        for (int i2 = 0; i2 < 4; ++i2) {
            int m = m0 + quad * 4 + i2;
            xs0[i2] = (float)Ahi[sw7(m, nh + l15)] + (float)Alo[sw7(m, nh + l15)];
            xs1[i2] = (float)Ahi[sw7(m, nh + 16 + l15)] + (float)Alo[sw7(m, nh + 16 + l15)];
        }
        __syncthreads();  // (3) all xs reads done before Contrib overlay

        // contrib = xs * (d + be2); stride 65 -> bank=(m+col)%32, 2-way free
#pragma unroll
        for (int i2 = 0; i2 < 4; ++i2) {
            int m = m0 + quad * 4 + i2;
            Contrib[m * 65 + nh + l15]      = (d0[i2] + b2v0) * xs0[i2];
            Contrib[m * 65 + nh + 16 + l15] = (d1[i2] + b2v1) * xs1[i2];
        }
        __syncthreads();  // (4)

        // ---- segmented sum over sorted dst runs, all data in LDS ----
        if (tid < 64) {
            int j = tid;
            float a = 0.f;
            int curNode = edstS[0];
            int runStart = 0;
            for (int ii = 0; ii < etile; ++ii) {
                a += Contrib[ii * 65 + j];
                bool last = (ii == etile - 1);
                int nxt = last ? -1 : edstS[ii + 1];
                if (last || nxt != curNode) {
                    bool complete = true;
                    if (runStart == 0 && offFS_ != e0) complete = false;
                    if (last && offLS_ != e0 + etile) complete = false;
                    if (complete) hneigh[(size_t)curNode * D + j] = a;
                    else atomicAdd(&hneigh[(size_t)curNode * D + j], a);
                    a = 0.f; curNode = nxt; runStart = ii + 1;
                }
            }
        }
        __syncthreads();  // (5) protect Abuf/edstS for next tile
    }
}

// ---------------------------------------------------------------------------
// Node MLP via MFMA: h2 = relu(h @ Wn + bn) in place; gate = h2 @ Wg + bg.
// ---------------------------------------------------------------------------
__global__ __launch_bounds__(256, 2) void node_mfma_kernel(
    float* __restrict__ h,     // [N,D] in: h_neigh, out: h2
    const float* __restrict__ Wn, const float* __restrict__ bn,
    const float* __restrict__ Wg, const float* __restrict__ bg,
    float* __restrict__ gate, int N, int T)
{
    __shared__ __attribute__((aligned(16))) f16 WNhi[64 * 64];
    __shared__ __attribute__((aligned(16))) f16 WNlo[64 * 64];
    __shared__ __attribute__((aligned(16))) f16 ANhi[64 * 64];
    __shared__ __attribute__((aligned(16))) f16 ANlo[64 * 64];

    const int tid = threadIdx.x;
    {
        int n = tid & 63;
        int kb = (tid >> 6) * 16;
        for (int kk = 0; kk < 16; ++kk) {
            int k = kb + kk;
            float v = Wn[k * 64 + n];
            f16 hh = (f16)v;
            WNhi[sw6(n, k)] = hh;
            WNlo[sw6(n, k)] = (f16)(v - (float)hh);
        }
    }

    const int w = tid >> 6;
    const int lane = tid & 63;
    const int l15 = lane & 15;
    const int quad = lane >> 4;
    const int m0 = w * 16;

    float bnv[4], wgv[4];
#pragma unroll
    for (int nt = 0; nt < 4; ++nt) {
        bnv[nt] = bn[nt * 16 + l15];
        wgv[nt] = Wg[nt * 16 + l15];
    }
    const float bgv = bg[0];

    __syncthreads();

    for (int tile = blockIdx.x; tile < T; tile += gridDim.x) {
        const int t0 = tile * 64;

        {
            int i = tid >> 2;
            int q = tid & 3;
            int node = min(t0 + i, N - 1);
            const float* p = h + (size_t)node * D + q * 16;
#pragma unroll
            for (int r = 0; r < 4; ++r) {
                float4 v = *(const float4*)(p + r * 4);
                int k = q * 16 + r * 4;
                f16x4 hv, lv;
                hv[0] = (f16)v.x; lv[0] = (f16)(v.x - (float)hv[0]);
                hv[1] = (f16)v.y; lv[1] = (f16)(v.y - (float)hv[1]);
                hv[2] = (f16)v.z; lv[2] = (f16)(v.z - (float)hv[2]);
                hv[3] = (f16)v.w; lv[3] = (f16)(v.w - (float)hv[3]);
                *(f16x4*)&ANhi[sw6(i, k)] = hv;
                *(f16x4*)&ANlo[sw6(i, k)] = lv;
            }
        }
        __syncthreads();

        f32x4 c[4] = {{0.f,0.f,0.f,0.f},{0.f,0.f,0.f,0.f},{0.f,0.f,0.f,0.f},{0.f,0.f,0.f,0.f}};
#pragma unroll
        for (int kt = 0; kt < 2; ++kt) {
            int k = kt * 32 + quad * 8;
            f16x8 ah = *(const f16x8*)&ANhi[sw6(m0 + l15, k)];
            f16x8 al = *(const f16x8*)&ANlo[sw6(m0 + l15, k)];
#pragma unroll
            for (int nt = 0; nt < 4; ++nt) {
                f16x8 bh = *(const f16x8*)&WNhi[sw6(nt * 16 + l15, k)];
                f16x8 bl = *(const f16x8*)&WNlo[sw6(nt * 16 + l15, k)];
                c[nt] = __builtin_amdgcn_mfma_f32_16x16x32_f16(ah, bh, c[nt], 0, 0, 0);
                c[nt] = __builtin_amdgcn_mfma_f32_16x16x32_f16(ah, bl, c[nt], 0, 0, 0);
                c[nt] = __builtin_amdgcn_mfma_f32_16x16x32_f16(al, bh, c[nt], 0, 0, 0);
            }
        }
        __syncthreads();

        float gpart[4] = {0.f, 0.f, 0.f, 0.f};
#pragma unroll
        for (int nt = 0; nt < 4; ++nt) {
            int n = nt * 16 + l15;
#pragma unroll
            for (int i2 = 0; i2 < 4; ++i2) {
                int m = t0 + m0 + quad * 4 + i2;
                float v = fmaxf(c[nt][i2] + bnv[nt], 0.f);
                if (m < N) h[(size_t)m * D + n] = v;
                gpart[i2] += v * wgv[nt];
            }
        }
#pragma unroll
        for (int s = 1; s < 16; s <<= 1) {
#pragma unroll
            for (int i2 = 0; i2 < 4; ++i2) gpart[i2] += __shfl_xor(gpart[i2], s);
        }
        if (l15 == 0) {
#pragma unroll
            for (int i2 = 0; i2 < 4; ++i2) {
                int m = t0 + m0 + quad * 4 + i2;
                if (m < N) gate[m] = gpart[i2] + bgv;
            }
        }
        __syncthreads();
    }
}

// ---------------------------------------------------------------------------
// Pool: one block per graph; softmax over gates, weighted sum, classifier.
// ---------------------------------------------------------------------------
__global__ __launch_bounds__(256) void pool_kernel(
    const float* __restrict__ h2,
    const float* __restrict__ gate,
    const int* __restrict__ gid,
    const float* __restrict__ Wfc, const float* __restrict__ bfc,
    float* __restrict__ out, int N, int C)
{
    int g = blockIdx.x;
    int tid = threadIdx.x;

    int lo = 0, hi = N;
    while (lo < hi) { int mid = (lo + hi) >> 1; if (gid[mid] < g) lo = mid + 1; else hi = mid; }
    int s = lo;
    hi = N;
    while (lo < hi) { int mid = (lo + hi) >> 1; if (gid[mid] < g + 1) lo = mid + 1; else hi = mid; }
    int e = lo;

    __shared__ float red[256];
    __shared__ float accs[4][D];
    __shared__ float dens[4];

    float m = -INFINITY;
    for (int i = s + tid; i < e; i += 256) m = fmaxf(m, gate[i]);
    red[tid] = m;
    __syncthreads();
    for (int w = 128; w > 0; w >>= 1) {
        if (tid < w) red[tid] = fmaxf(red[tid], red[tid + w]);
        __syncthreads();
    }
    float gmax = red[0];
    __syncthreads();

    int f = tid & (D - 1);
    int grp = tid >> 6;
    float acc = 0.0f, den = 0.0f;
    for (int i = s + grp; i < e; i += 4) {
        float w = expf(gate[i] - gmax);
        acc += w * h2[(size_t)i * D + f];
        if (f == 0) den += w;
    }
    accs[grp][f] = acc;
    if (f == 0) dens[grp] = den;
    __syncthreads();

    if (tid < D) {
        float p = accs[0][tid] + accs[1][tid] + accs[2][tid] + accs[3][tid];
        float dn = dens[0] + dens[1] + dens[2] + dens[3];
        p = (e > s) ? (p / dn) : 0.0f;
        red[tid] = p;
    }
    __syncthreads();

    if (tid < C) {
        float o = bfc[tid];
#pragma unroll
        for (int k = 0; k < D; ++k) o += red[k] * Wfc[k * C + tid];
        out[g * C + tid] = o;
    }
}

extern "C" void kernel_launch(void* const* d_in, const int* in_sizes, int n_in,
                              void* d_out, int out_size, void* d_ws, size_t ws_size,
                              hipStream_t stream) {
    const float* x   = (const float*)d_in[0];
    const float* We1 = (const float*)d_in[1];
    const float* be1 = (const float*)d_in[2];
    const float* We2 = (const float*)d_in[3];
    const float* be2 = (const float*)d_in[4];
    const float* Wn  = (const float*)d_in[5];
    const float* bn  = (const float*)d_in[6];
    const float* Wg  = (const float*)d_in[7];
    const float* bg  = (const float*)d_in[8];
    const float* Wfc = (const float*)d_in[9];
    const float* bfc = (const float*)d_in[10];
    const int* src = (const int*)d_in[11];
    const int* dst = (const int*)d_in[12];
    const int* gid = (const int*)d_in[13];

    const int N = in_sizes[0] / D;
    const int E = in_sizes[11];
    const int C = 10;
    const int G = out_size / C;

    float* hneigh = (float*)d_ws;                 // [N*D]
    float* gate   = hneigh + (size_t)N * D;       // [N]
    int*   deg    = (int*)(gate + N);             // [N]
    int*   off    = deg + N;                      // [N+1]
    int*   cursor = off + N + 1;                  // [N]
    int*   part   = cursor + N;                   // [128]
    int*   esrc   = part + 128;                   // [E]
    int*   edstg  = esrc + E;                     // [E]
    float* outp   = (float*)d_out;

    const int Bp = (N + 1023) / 1024;
    const int Te = (E + 31) / 32;
    const int Tn = (N + 63) / 64;

    hipMemsetAsync(hneigh, 0, (size_t)N * D * sizeof(float), stream);
    hipMemsetAsync(deg, 0, (size_t)N * sizeof(int), stream);

    hist_kernel<<<(E + 255) / 256, 256, 0, stream>>>(dst, deg, E);
    scan_part<<<Bp, 256, 0, stream>>>(deg, part, N);
    scan_mid<<<1, 64, 0, stream>>>(part, off + N, Bp);
    scan_out<<<Bp, 256, 0, stream>>>(deg, part, off, cursor, N);
    fill_kernel<<<(E + 255) / 256, 256, 0, stream>>>(dst, src, cursor, esrc, edstg, E);

    edge_mfma_kernel<<<512, 256, 0, stream>>>(x, We1, be1, We2, be2,
                                              off, esrc, edstg, hneigh, N, E, Te);
    node_mfma_kernel<<<1024, 256, 0, stream>>>(hneigh, Wn, bn, Wg, bg, gate, N, Tn);
    pool_kernel<<<G, 256, 0, stream>>>(hneigh, gate, gid, Wfc, bfc, outp, N, C);
}

// Round 6
// 639.552 us; speedup vs baseline: 8.6215x; 1.3925x over previous
//
#include <hip/hip_runtime.h>
#include <hip/hip_bf16.h>

#define D 64

typedef _Float16 f16;
typedef _Float16 f16x4 __attribute__((ext_vector_type(4)));
typedef _Float16 f16x8 __attribute__((ext_vector_type(8)));
typedef float f32x4 __attribute__((ext_vector_type(4)));

// XOR-swizzled f16 index (16B-chunk swizzle): conflict-free b128 frag reads.
__device__ __forceinline__ int sw7(int m, int k) {  // row stride 128 f16
    return (m << 7) + (((k >> 3) ^ (m & 7)) << 3) + (k & 7);
}
__device__ __forceinline__ int sw6(int m, int k) {  // row stride 64 f16
    return (m << 6) + ((((k >> 3) ^ (m & 7)) & 7) << 3) + (k & 7);
}

// ---------------------------------------------------------------------------
// CSR build: histogram, hierarchical scan, fill (int2 src,dst grouped by dst).
// ---------------------------------------------------------------------------
__global__ void hist_kernel(const int* __restrict__ dst, int* __restrict__ deg, int E)
{
    int e = blockIdx.x * 256 + threadIdx.x;
    if (e < E) atomicAdd(&deg[dst[e]], 1);
}

__global__ void scan_part(const int* __restrict__ deg, int* __restrict__ part, int N)
{
    __shared__ int red[256];
    int b = blockIdx.x, t = threadIdx.x;
    int base = b * 1024 + t * 4;
    int s = 0;
#pragma unroll
    for (int u = 0; u < 4; ++u) { int i = base + u; if (i < N) s += deg[i]; }
    red[t] = s; __syncthreads();
    for (int w = 128; w > 0; w >>= 1) {
        if (t < w) red[t] += red[t + w];
        __syncthreads();
    }
    if (t == 0) part[b] = red[0];
}

__global__ void scan_mid(int* __restrict__ part, int* __restrict__ offN, int B)
{
    if (threadIdx.x == 0) {
        int run = 0;
        for (int b = 0; b < B; ++b) { int v = part[b]; part[b] = run; run += v; }
        *offN = run;  // off[N] = E
    }
}

__global__ void scan_out(const int* __restrict__ deg, const int* __restrict__ part,
                         int* __restrict__ off, int* __restrict__ cursor, int N)
{
    __shared__ int lds[256];
    int b = blockIdx.x, t = threadIdx.x;
    int base = b * 1024 + t * 4;
    int dv[4]; int s = 0;
#pragma unroll
    for (int u = 0; u < 4; ++u) { int i = base + u; dv[u] = (i < N) ? deg[i] : 0; s += dv[u]; }
    lds[t] = s; __syncthreads();
    for (int d2 = 1; d2 < 256; d2 <<= 1) {
        int v = (t >= d2) ? lds[t - d2] : 0;
        __syncthreads();
        lds[t] += v;
        __syncthreads();
    }
    int run = part[b] + lds[t] - s;  // exclusive prefix
#pragma unroll
    for (int u = 0; u < 4; ++u) {
        int i = base + u;
        if (i < N) { off[i] = run; cursor[i] = run; }
        run += dv[u];
    }
}

__global__ void fill_kernel(const int* __restrict__ dst, const int* __restrict__ src,
                            int* __restrict__ cursor, int2* __restrict__ eix, int E)
{
    int e = blockIdx.x * 256 + threadIdx.x;
    if (e < E) {
        int d = dst[e];
        int p = atomicAdd(&cursor[d], 1);
        eix[p] = make_int2(src[e], d);
    }
}

// ---------------------------------------------------------------------------
// Edge MLP via MFMA. Weights live in VGPR fragments (loaded once per block).
// A = f16 hi+lo (exact), B = f16 (2-term split). Tile = 32 sorted edges,
// register-prefetched gather (t+1 loads overlap tile t compute).
// ---------------------------------------------------------------------------
__global__ __launch_bounds__(256, 3) void edge_mfma_kernel(
    const float* __restrict__ x,
    const float* __restrict__ We1, const float* __restrict__ be1,
    const float* __restrict__ We2, const float* __restrict__ be2,
    const int* __restrict__ off, const int2* __restrict__ eix,
    float* __restrict__ hneigh, int N, int E, int T)
{
    __shared__ __attribute__((aligned(16))) f16 Ahi[32 * 128];   // 8KB
    __shared__ __attribute__((aligned(16))) f16 Alo[32 * 128];   // 8KB
    __shared__ __attribute__((aligned(16))) f16 Hbuf[32 * 64];   // 4KB
    __shared__ __attribute__((aligned(16))) float Contrib[32 * 65]; // 8.3KB
    __shared__ int edstS[32];
    __shared__ int offF_, offL_;

    const int tid = threadIdx.x;
    const int w = tid >> 6;
    const int lane = tid & 63;
    const int l15 = lane & 15;
    const int quad = lane >> 4;
    const int m0 = (w & 1) * 16;        // edge strip within tile
    const int nh = (w >> 1) * 32;       // feature half

    // ---- weight fragments in registers (loop-invariant) ----
    f16x8 wb1[4][2];
#pragma unroll
    for (int kt = 0; kt < 4; ++kt)
#pragma unroll
        for (int nf = 0; nf < 2; ++nf) {
            int n = nh + nf * 16 + l15;
#pragma unroll
            for (int j = 0; j < 8; ++j)
                wb1[kt][nf][j] = (f16)We1[(kt * 32 + quad * 8 + j) * 64 + n];
        }
    f16x8 wb2[2][2];
#pragma unroll
    for (int kt = 0; kt < 2; ++kt)
#pragma unroll
        for (int nf = 0; nf < 2; ++nf) {
            int n = nh + nf * 16 + l15;
#pragma unroll
            for (int j = 0; j < 8; ++j)
                wb2[kt][nf][j] = (f16)We2[(kt * 32 + quad * 8 + j) * 64 + n];
        }

    const float b1v0 = be1[nh + l15], b1v1 = be1[nh + 16 + l15];
    const float b2v0 = be2[nh + l15], b2v1 = be2[nh + 16 + l15];

    // staging role: thread = (edge i, 8-feature chunk c)
    const int i = tid >> 3;
    const int c = tid & 7;

    // ---- prologue: prefetch tile0 ----
    int2 pe;
    float4 pf0, pf1, pf2, pf3;
    {
        int ei = min(blockIdx.x * 32 + i, E - 1);
        pe = eix[ei];
        const float* ps = x + (size_t)pe.x * D + c * 8;
        const float* pd = x + (size_t)pe.y * D + c * 8;
        pf0 = *(const float4*)ps;
        pf1 = *(const float4*)(ps + 4);
        pf2 = *(const float4*)pd;
        pf3 = *(const float4*)(pd + 4);
    }

    for (int tile = blockIdx.x; tile < T; tile += gridDim.x) {
        const int e0 = tile * 32;
        const int etile = min(32, E - e0);

        // ---- convert prefetched regs -> LDS A ----
        {
            float sv[8] = {pf0.x, pf0.y, pf0.z, pf0.w, pf1.x, pf1.y, pf1.z, pf1.w};
            float dv[8] = {pf2.x, pf2.y, pf2.z, pf2.w, pf3.x, pf3.y, pf3.z, pf3.w};
            f16x8 sh, sl, dh, dl;
#pragma unroll
            for (int r = 0; r < 8; ++r) {
                sh[r] = (f16)sv[r]; sl[r] = (f16)(sv[r] - (float)sh[r]);
                dh[r] = (f16)dv[r]; dl[r] = (f16)(dv[r] - (float)dh[r]);
            }
            *(f16x8*)&Ahi[sw7(i, c * 8)] = sh;
            *(f16x8*)&Alo[sw7(i, c * 8)] = sl;
            *(f16x8*)&Ahi[sw7(i, 64 + c * 8)] = dh;
            *(f16x8*)&Alo[sw7(i, 64 + c * 8)] = dl;
            if (c == 0) edstS[i] = (e0 + i < E) ? pe.y : N;  // sentinel for ghosts
            if (tid == 0)   offF_ = off[pe.y];
            if (tid == 248) offL_ = off[pe.y + 1];  // i=31: dst of last real edge
        }
        __syncthreads();  // (1)

        // ---- prefetch next tile (latency overlaps the whole tile compute) ----
        {
            int tn = tile + gridDim.x;
            if (tn < T) {
                int ei = min(tn * 32 + i, E - 1);
                pe = eix[ei];
                const float* ps = x + (size_t)pe.x * D + c * 8;
                const float* pd = x + (size_t)pe.y * D + c * 8;
                pf0 = *(const float4*)ps;
                pf1 = *(const float4*)(ps + 4);
                pf2 = *(const float4*)pd;
                pf3 = *(const float4*)(pd + 4);
            }
        }

        // ---- GEMM1: [32,128]@[128,64], A split 2-term ----
        f32x4 c0 = {0.f, 0.f, 0.f, 0.f}, c1 = {0.f, 0.f, 0.f, 0.f};
#pragma unroll
        for (int kt = 0; kt < 4; ++kt) {
            int k = kt * 32 + quad * 8;
            f16x8 ah = *(const f16x8*)&Ahi[sw7(m0 + l15, k)];
            f16x8 al = *(const f16x8*)&Alo[sw7(m0 + l15, k)];
            c0 = __builtin_amdgcn_mfma_f32_16x16x32_f16(ah, wb1[kt][0], c0, 0, 0, 0);
            c0 = __builtin_amdgcn_mfma_f32_16x16x32_f16(al, wb1[kt][0], c0, 0, 0, 0);
            c1 = __builtin_amdgcn_mfma_f32_16x16x32_f16(ah, wb1[kt][1], c1, 0, 0, 0);
            c1 = __builtin_amdgcn_mfma_f32_16x16x32_f16(al, wb1[kt][1], c1, 0, 0, 0);
        }

        // relu + f16, C-layout -> LDS (A-layout for GEMM2)
#pragma unroll
        for (int i2 = 0; i2 < 4; ++i2) {
            int m = m0 + quad * 4 + i2;
            Hbuf[sw6(m, nh + l15)]      = (f16)fmaxf(c0[i2] + b1v0, 0.f);
            Hbuf[sw6(m, nh + 16 + l15)] = (f16)fmaxf(c1[i2] + b1v1, 0.f);
        }
        __syncthreads();  // (2)

        // ---- GEMM2: [32,64]@[64,64] ----
        f32x4 d0 = {0.f, 0.f, 0.f, 0.f}, d1 = {0.f, 0.f, 0.f, 0.f};
#pragma unroll
        for (int kt = 0; kt < 2; ++kt) {
            int k = kt * 32 + quad * 8;
            f16x8 ah = *(const f16x8*)&Hbuf[sw6(m0 + l15, k)];
            d0 = __builtin_amdgcn_mfma_f32_16x16x32_f16(ah, wb2[kt][0], d0, 0, 0, 0);
            d1 = __builtin_amdgcn_mfma_f32_16x16x32_f16(ah, wb2[kt][1], d1, 0, 0, 0);
        }

        // contrib = xs * (d + be2); xs reconstructed exactly from A hi+lo
#pragma unroll
        for (int i2 = 0; i2 < 4; ++i2) {
            int m = m0 + quad * 4 + i2;
            float xs0 = (float)Ahi[sw7(m, nh + l15)] + (float)Alo[sw7(m, nh + l15)];
            float xs1 = (float)Ahi[sw7(m, nh + 16 + l15)] + (float)Alo[sw7(m, nh + 16 + l15)];
            Contrib[m * 65 + nh + l15]      = (d0[i2] + b2v0) * xs0;
            Contrib[m * 65 + nh + 16 + l15] = (d1[i2] + b2v1) * xs1;
        }
        __syncthreads();  // (3)

        // ---- segmented sum over sorted dst runs (fixed 32, sentinel-padded) ----
        if (tid < 64) {
            int j = tid;
            float a = 0.f;
            int cur = edstS[0];
            int runStart = 0;
#pragma unroll
            for (int ii = 0; ii < 32; ++ii) {
                a += Contrib[ii * 65 + j];
                int nxt = (ii < 31) ? edstS[ii + 1] : -1;
                if (nxt != cur) {
                    bool isLast = (ii == 31) || (nxt >= N);
                    bool complete = (runStart > 0 || offF_ == e0) &&
                                    (!isLast || offL_ == e0 + etile);
                    if (complete) hneigh[(size_t)cur * D + j] = a;
                    else atomicAdd(&hneigh[(size_t)cur * D + j], a);
                    a = 0.f; cur = nxt; runStart = ii + 1;
                }
            }
        }
        __syncthreads();  // (4)
    }
}

// ---------------------------------------------------------------------------
// Node MLP via MFMA, weights in VGPR fragments, 2-term split.
// h2 = relu(h @ Wn + bn) in place; gate = h2 @ Wg + bg.
// ---------------------------------------------------------------------------
__global__ __launch_bounds__(256, 4) void node_mfma_kernel(
    float* __restrict__ h,     // [N,D] in: h_neigh, out: h2
    const float* __restrict__ Wn, const float* __restrict__ bn,
    const float* __restrict__ Wg, const float* __restrict__ bg,
    float* __restrict__ gate, int N, int T)
{
    __shared__ __attribute__((aligned(16))) f16 ANhi[64 * 64];  // 8KB
    __shared__ __attribute__((aligned(16))) f16 ANlo[64 * 64];  // 8KB

    const int tid = threadIdx.x;
    const int w = tid >> 6;
    const int lane = tid & 63;
    const int l15 = lane & 15;
    const int quad = lane >> 4;
    const int m0 = w * 16;

    f16x8 wn[2][4];
#pragma unroll
    for (int kt = 0; kt < 2; ++kt)
#pragma unroll
        for (int nf = 0; nf < 4; ++nf) {
            int n = nf * 16 + l15;
#pragma unroll
            for (int j = 0; j < 8; ++j)
                wn[kt][nf][j] = (f16)Wn[(kt * 32 + quad * 8 + j) * 64 + n];
        }

    float bnv[4], wgv[4];
#pragma unroll
    for (int nt = 0; nt < 4; ++nt) {
        bnv[nt] = bn[nt * 16 + l15];
        wgv[nt] = Wg[nt * 16 + l15];
    }
    const float bgv = bg[0];

    for (int tile = blockIdx.x; tile < T; tile += gridDim.x) {
        const int t0 = tile * 64;

        {
            int i = tid >> 2;
            int q = tid & 3;
            int node = min(t0 + i, N - 1);
            const float* p = h + (size_t)node * D + q * 16;
#pragma unroll
            for (int r = 0; r < 4; ++r) {
                float4 v = *(const float4*)(p + r * 4);
                int k = q * 16 + r * 4;
                f16x4 hv, lv;
                hv[0] = (f16)v.x; lv[0] = (f16)(v.x - (float)hv[0]);
                hv[1] = (f16)v.y; lv[1] = (f16)(v.y - (float)hv[1]);
                hv[2] = (f16)v.z; lv[2] = (f16)(v.z - (float)hv[2]);
                hv[3] = (f16)v.w; lv[3] = (f16)(v.w - (float)hv[3]);
                *(f16x4*)&ANhi[sw6(i, k)] = hv;
                *(f16x4*)&ANlo[sw6(i, k)] = lv;
            }
        }
        __syncthreads();

        f32x4 cacc[4] = {{0.f,0.f,0.f,0.f},{0.f,0.f,0.f,0.f},{0.f,0.f,0.f,0.f},{0.f,0.f,0.f,0.f}};
#pragma unroll
        for (int kt = 0; kt < 2; ++kt) {
            int k = kt * 32 + quad * 8;
            f16x8 ah = *(const f16x8*)&ANhi[sw6(m0 + l15, k)];
            f16x8 al = *(const f16x8*)&ANlo[sw6(m0 + l15, k)];
#pragma unroll
            for (int nf = 0; nf < 4; ++nf) {
                cacc[nf] = __builtin_amdgcn_mfma_f32_16x16x32_f16(ah, wn[kt][nf], cacc[nf], 0, 0, 0);
                cacc[nf] = __builtin_amdgcn_mfma_f32_16x16x32_f16(al, wn[kt][nf], cacc[nf], 0, 0, 0);
            }
        }
        __syncthreads();  // AN reads done before next-iter staging

        float gpart[4] = {0.f, 0.f, 0.f, 0.f};
#pragma unroll
        for (int nt = 0; nt < 4; ++nt) {
            int n = nt * 16 + l15;
#pragma unroll
            for (int i2 = 0; i2 < 4; ++i2) {
                int m = t0 + m0 + quad * 4 + i2;
                float v = fmaxf(cacc[nt][i2] + bnv[nt], 0.f);
                if (m < N) h[(size_t)m * D + n] = v;
                gpart[i2] += v * wgv[nt];
            }
        }
#pragma unroll
        for (int s = 1; s < 16; s <<= 1) {
#pragma unroll
            for (int i2 = 0; i2 < 4; ++i2) gpart[i2] += __shfl_xor(gpart[i2], s);
        }
        if (l15 == 0) {
#pragma unroll
            for (int i2 = 0; i2 < 4; ++i2) {
                int m = t0 + m0 + quad * 4 + i2;
                if (m < N) gate[m] = gpart[i2] + bgv;
            }
        }
    }
}

// ---------------------------------------------------------------------------
// Pool: one block per graph; softmax over gates, weighted sum, classifier.
// ---------------------------------------------------------------------------
__global__ __launch_bounds__(256) void pool_kernel(
    const float* __restrict__ h2,
    const float* __restrict__ gate,
    const int* __restrict__ gid,
    const float* __restrict__ Wfc, const float* __restrict__ bfc,
    float* __restrict__ out, int N, int C)
{
    int g = blockIdx.x;
    int tid = threadIdx.x;

    int lo = 0, hi = N;
    while (lo < hi) { int mid = (lo + hi) >> 1; if (gid[mid] < g) lo = mid + 1; else hi = mid; }
    int s = lo;
    hi = N;
    while (lo < hi) { int mid = (lo + hi) >> 1; if (gid[mid] < g + 1) lo = mid + 1; else hi = mid; }
    int e = lo;

    __shared__ float red[256];
    __shared__ float accs[4][D];
    __shared__ float dens[4];

    float m = -INFINITY;
    for (int i = s + tid; i < e; i += 256) m = fmaxf(m, gate[i]);
    red[tid] = m;
    __syncthreads();
    for (int w = 128; w > 0; w >>= 1) {
        if (tid < w) red[tid] = fmaxf(red[tid], red[tid + w]);
        __syncthreads();
    }
    float gmax = red[0];
    __syncthreads();

    int f = tid & (D - 1);
    int grp = tid >> 6;
    float acc = 0.0f, den = 0.0f;
    for (int i = s + grp; i < e; i += 4) {
        float w = expf(gate[i] - gmax);
        acc += w * h2[(size_t)i * D + f];
        if (f == 0) den += w;
    }
    accs[grp][f] = acc;
    if (f == 0) dens[grp] = den;
    __syncthreads();

    if (tid < D) {
        float p = accs[0][tid] + accs[1][tid] + accs[2][tid] + accs[3][tid];
        float dn = dens[0] + dens[1] + dens[2] + dens[3];
        p = (e > s) ? (p / dn) : 0.0f;
        red[tid] = p;
    }
    __syncthreads();

    if (tid < C) {
        float o = bfc[tid];
#pragma unroll
        for (int k = 0; k < D; ++k) o += red[k] * Wfc[k * C + tid];
        out[g * C + tid] = o;
    }
}

extern "C" void kernel_launch(void* const* d_in, const int* in_sizes, int n_in,
                              void* d_out, int out_size, void* d_ws, size_t ws_size,
                              hipStream_t stream) {
    const float* x   = (const float*)d_in[0];
    const float* We1 = (const float*)d_in[1];
    const float* be1 = (const float*)d_in[2];
    const float* We2 = (const float*)d_in[3];
    const float* be2 = (const float*)d_in[4];
    const float* Wn  = (const float*)d_in[5];
    const float* bn  = (const float*)d_in[6];
    const float* Wg  = (const float*)d_in[7];
    const float* bg  = (const float*)d_in[8];
    const float* Wfc = (const float*)d_in[9];
    const float* bfc = (const float*)d_in[10];
    const int* src = (const int*)d_in[11];
    const int* dst = (const int*)d_in[12];
    const int* gid = (const int*)d_in[13];

    const int N = in_sizes[0] / D;
    const int E = in_sizes[11];
    const int C = 10;
    const int G = out_size / C;

    // workspace layout (4B elements); eix kept 8B-aligned
    float* hneigh = (float*)d_ws;                     // [(N+1)*64]  (+1 = sentinel row)
    float* gate   = hneigh + (size_t)(N + 1) * D;     // [N]
    int*   deg    = (int*)(gate + N);                 // [N]
    int*   cursor = deg + N;                          // [N]
    int*   part   = cursor + N;                       // [128]
    int*   off    = part + 128;                       // [N+1]
    int*   pad    = off + N + 1;                      // [1] align
    int2*  eixp   = (int2*)(pad + 1);                 // [E]
    float* outp   = (float*)d_out;

    const int Bp = (N + 1023) / 1024;
    const int Te = (E + 31) / 32;
    const int Tn = (N + 63) / 64;

    hipMemsetAsync(hneigh, 0, (size_t)(N + 1) * D * sizeof(float), stream);
    hipMemsetAsync(deg, 0, (size_t)N * sizeof(int), stream);

    hist_kernel<<<(E + 255) / 256, 256, 0, stream>>>(dst, deg, E);
    scan_part<<<Bp, 256, 0, stream>>>(deg, part, N);
    scan_mid<<<1, 64, 0, stream>>>(part, off + N, Bp);
    scan_out<<<Bp, 256, 0, stream>>>(deg, part, off, cursor, N);
    fill_kernel<<<(E + 255) / 256, 256, 0, stream>>>(dst, src, cursor, eixp, E);

    edge_mfma_kernel<<<768, 256, 0, stream>>>(x, We1, be1, We2, be2,
                                              off, eixp, hneigh, N, E, Te);
    node_mfma_kernel<<<1024, 256, 0, stream>>>(hneigh, Wn, bn, Wg, bg, gate, N, Tn);
    pool_kernel<<<G, 256, 0, stream>>>(hneigh, gate, gid, Wfc, bfc, outp, N, C);
}